// Round 4
// baseline (295.924 us; speedup 1.0000x reference)
//
#include <hip/hip_runtime.h>
#include <math.h>

#define N_NODES 50000
#define N_EDGES 800000
#define BATCH   4
#define C1      64
#define C2      32
#define BN      (BATCH * N_NODES)
#define NBLK_N  ((N_NODES + 255) / 256)

// ---------------- CSR build ----------------

__global__ void k_zero(int* __restrict__ cnt) {
    int n = blockIdx.x * 256 + threadIdx.x;
    if (n < N_NODES) cnt[n] = 0;
}

// histogram of in-degree (dst)
__global__ void k_hist(const int* __restrict__ ei, int* __restrict__ cnt) {
    int e = blockIdx.x * 256 + threadIdx.x;
    if (e >= N_EDGES) return;
    atomicAdd(&cnt[ei[N_EDGES + e]], 1);
}

// single-block: per-residue (n&7) totals of cnt -> exclusive prefix -> cur8 bases
__global__ __launch_bounds__(1024) void k_bcur(const int* __restrict__ cnt,
                                               int* __restrict__ cur8) {
    __shared__ int buf[1024];
    int tid = threadIdx.x;
    int acc = 0;
    for (int i = tid; i < N_NODES; i += 1024) acc += cnt[i];  // i&7 == tid&7 (1024%8==0)
    buf[tid] = acc;
    __syncthreads();
    for (int s = 512; s >= 8; s >>= 1) {
        if (tid < s) buf[tid] += buf[tid + s];   // s multiple of 8 -> residue preserved
        __syncthreads();
    }
    if (tid == 0) {
        int base = 0;
        for (int r = 0; r < 8; r++) { int t = buf[r]; cur8[r] = base; base += t; }
    }
}

// allocator (bucketed by n&7, per-bucket bump) + fused xd = x * dinv
__global__ __launch_bounds__(256) void k_alloc_xd(
        const int* __restrict__ cnt, const float* __restrict__ x,
        int* __restrict__ row, int* __restrict__ cursor, float* __restrict__ dinv,
        float* __restrict__ xd, int* __restrict__ cur8) {
    int t = blockIdx.x * 256 + threadIdx.x;

    if (blockIdx.x < NBLK_N) {   // allocator region (uniform per block)
        int lane = threadIdx.x & 63;
        int v = (t < N_NODES) ? cnt[t] : 0;
        // stride-8 segmented inclusive scan over the wave (residue = lane&7)
        int xs = v;
#pragma unroll
        for (int s = 8; s < 64; s <<= 1) {
            int y = __shfl_up(xs, s, 64);
            if (lane >= s) xs += y;
        }
        int base = 0;
        if (lane >= 56) base = atomicAdd(&cur8[lane & 7], xs);  // xs = residue total
        base = __shfl(base, 56 + (lane & 7), 64);
        if (t < N_NODES) {
            int r = base + (xs - v);
            row[t] = r;
            cursor[t] = r;
            dinv[t] = rsqrtf((float)(v + 1));   // +1 self-loop
        }
    }

    if (t < BN) {
        int n = t % N_NODES;
        float di = rsqrtf((float)(cnt[n] + 1));
        xd[t] = x[t] * di;
    }
}

// bucketed fill: block bid handles edges with (dst&7)==(bid&7) -> single-writer-XCD
// csr regions (with blockIdx%8 -> XCD round-robin heuristic)
__global__ void k_fill(const int* __restrict__ ei, int* __restrict__ cursor,
                       int* __restrict__ csr) {
    int bid = blockIdx.x;
    int r = bid & 7;
    int e = (bid >> 3) * 256 + threadIdx.x;
    if (e >= N_EDGES) return;
    int d = ei[N_EDGES + e];
    if ((d & 7) != r) return;
    int s = ei[e];
    int pos = atomicAdd(&cursor[d], 1);
    csr[pos] = s;
}

// ---------------- compute ----------------

// fused layer1 aggregation + dense 1->64 (relu) -> 64x32 matvec; y2 = dinv * (h1@W2)
__global__ __launch_bounds__(256) void k_l1l2(
        const float* __restrict__ dinv, const float* __restrict__ xd,
        const int* __restrict__ row, const int* __restrict__ cnt,
        const int* __restrict__ csr,
        const float* __restrict__ W1, const float* __restrict__ b1,
        const float* __restrict__ W2,
        float* __restrict__ y2) {
    __shared__ float sW1[C1], sb1[C1], sW2[C1 * C2];
    int lt = threadIdx.x;
    for (int i = lt; i < C1; i += 256) { sW1[i] = W1[i]; sb1[i] = b1[i]; }
    for (int i = lt; i < C1 * C2; i += 256) sW2[i] = W2[i];
    __syncthreads();

    int t = blockIdx.x * 256 + lt;
    if (t >= BN) return;
    int n = t % N_NODES;
    int base = t - n;                 // b*N
    float di = dinv[n];

    float s = xd[t];                  // self-loop
    int r0 = row[n], r1 = r0 + cnt[n];
    int k = r0;
    for (; k + 1 < r1; k += 2) {
        int s0 = csr[k], s1 = csr[k + 1];
        s += xd[base + s0] + xd[base + s1];
    }
    if (k < r1) s += xd[base + csr[k]];
    float px = di * s;

    float acc[C2];
#pragma unroll
    for (int j = 0; j < C2; j++) acc[j] = 0.0f;

    for (int c = 0; c < C1; c++) {
        float h = fmaxf(px * sW1[c] + sb1[c], 0.0f);
        const float4* rw = (const float4*)&sW2[c * C2];
#pragma unroll
        for (int j4 = 0; j4 < C2 / 4; j4++) {
            float4 w = rw[j4];
            acc[4 * j4 + 0] += h * w.x;
            acc[4 * j4 + 1] += h * w.y;
            acc[4 * j4 + 2] += h * w.z;
            acc[4 * j4 + 3] += h * w.w;
        }
    }

    float4* yo = (float4*)&y2[(size_t)t * C2];
#pragma unroll
    for (int j4 = 0; j4 < C2 / 4; j4++) {
        float4 v;
        v.x = acc[4 * j4 + 0] * di;
        v.y = acc[4 * j4 + 1] * di;
        v.z = acc[4 * j4 + 2] * di;
        v.w = acc[4 * j4 + 3] * di;
        yo[j4] = v;
    }
}

// layer-2 aggregation: z2[b,n,:] = y2[b,n,:] + sum_{s in in(n)} y2[b,s,:]
__global__ __launch_bounds__(256) void k_agg2(
        const float* __restrict__ y2, const int* __restrict__ row,
        const int* __restrict__ cnt, const int* __restrict__ csr,
        float* __restrict__ z2) {
    int tid = blockIdx.x * 256 + threadIdx.x;
    if (tid >= BN * 8) return;
    int j4  = tid & 7;
    int idx = tid >> 3;               // b*N + n
    int n = idx % N_NODES;
    int base = idx - n;               // b*N
    const float4* Y = (const float4*)y2;

    float4 a = Y[(size_t)idx * 8 + j4];   // self
    int r0 = row[n], r1 = r0 + cnt[n];
    int k = r0;
    for (; k + 1 < r1; k += 2) {
        int s0 = csr[k], s1 = csr[k + 1];
        float4 v0 = Y[(size_t)(base + s0) * 8 + j4];
        float4 v1 = Y[(size_t)(base + s1) * 8 + j4];
        a.x += v0.x + v1.x; a.y += v0.y + v1.y;
        a.z += v0.z + v1.z; a.w += v0.w + v1.w;
    }
    if (k < r1) {
        float4 v = Y[(size_t)(base + csr[k]) * 8 + j4];
        a.x += v.x; a.y += v.y; a.z += v.z; a.w += v.w;
    }
    ((float4*)z2)[(size_t)idx * 8 + j4] = a;
}

// layer-2 epilogue (relu(dinv*z2+b2)) + layer-3 transform: y3 = dinv*(h2@W3)
__global__ void k_l3(const float* __restrict__ dinv, const float* __restrict__ z2,
                     const float* __restrict__ b2, const float* __restrict__ W3,
                     float* __restrict__ y3) {
    int t = blockIdx.x * 256 + threadIdx.x;
    if (t >= BN) return;
    int n = t % N_NODES;
    float di = dinv[n];
    const float4* Z = (const float4*)&z2[(size_t)t * C2];
    float acc = 0.0f;
#pragma unroll
    for (int j4 = 0; j4 < C2 / 4; j4++) {
        float4 z = Z[j4];
        acc += fmaxf(di * z.x + b2[4 * j4 + 0], 0.0f) * W3[4 * j4 + 0];
        acc += fmaxf(di * z.y + b2[4 * j4 + 1], 0.0f) * W3[4 * j4 + 1];
        acc += fmaxf(di * z.z + b2[4 * j4 + 2], 0.0f) * W3[4 * j4 + 2];
        acc += fmaxf(di * z.w + b2[4 * j4 + 3], 0.0f) * W3[4 * j4 + 3];
    }
    y3[t] = acc * di;
}

// layer-3 aggregation + sigmoid output
__global__ void k_agg3out(const float* __restrict__ dinv, const float* __restrict__ y3,
                          const int* __restrict__ row, const int* __restrict__ cnt,
                          const int* __restrict__ csr,
                          const float* __restrict__ b3, float* __restrict__ out) {
    int t = blockIdx.x * 256 + threadIdx.x;
    if (t >= BN) return;
    int n = t % N_NODES;
    int base = t - n;
    float a = y3[t];                  // self
    int r0 = row[n], r1 = r0 + cnt[n];
    int k = r0;
    for (; k + 1 < r1; k += 2) {
        int s0 = csr[k], s1 = csr[k + 1];
        a += y3[base + s0] + y3[base + s1];
    }
    if (k < r1) a += y3[base + csr[k]];
    float v = dinv[n] * a + b3[0];
    out[t] = 1.0f / (1.0f + expf(-v));
}

// ---------------- launch ----------------

extern "C" void kernel_launch(void* const* d_in, const int* in_sizes, int n_in,
                              void* d_out, int out_size, void* d_ws, size_t ws_size,
                              hipStream_t stream) {
    const float* x   = (const float*)d_in[0];
    const int*   ei  = (const int*)d_in[1];
    const float* W1  = (const float*)d_in[2];
    const float* b1  = (const float*)d_in[3];
    const float* W2  = (const float*)d_in[4];
    const float* b2  = (const float*)d_in[5];
    const float* W3  = (const float*)d_in[6];
    const float* b3  = (const float*)d_in[7];
    float* out = (float*)d_out;

    char* ws = (char*)d_ws;
    size_t off = 0;
    auto carve = [&](size_t bytes) {
        void* p = ws + off;
        off = (off + bytes + 255) & ~(size_t)255;
        return p;
    };
    int*   cnt    = (int*)  carve(N_NODES * 4);
    int*   row    = (int*)  carve(N_NODES * 4);
    int*   cursor = (int*)  carve(N_NODES * 4);
    float* dinv   = (float*)carve(N_NODES * 4);
    int*   csr    = (int*)  carve(N_EDGES * 4);
    float* xd     = (float*)carve(BN * 4);
    float* y2     = (float*)carve((size_t)BN * C2 * 4);
    float* z2     = (float*)carve((size_t)BN * C2 * 4);
    float* y3     = (float*)carve(BN * 4);
    int*   cur8   = (int*)  carve(8 * 4);

    dim3 blk(256);

    k_zero     <<<NBLK_N, blk, 0, stream>>>(cnt);
    k_hist     <<<(N_EDGES + 255) / 256, blk, 0, stream>>>(ei, cnt);
    k_bcur     <<<1, 1024, 0, stream>>>(cnt, cur8);
    k_alloc_xd <<<(BN + 255) / 256, blk, 0, stream>>>(cnt, x, row, cursor, dinv, xd, cur8);
    k_fill     <<<8 * ((N_EDGES + 255) / 256), blk, 0, stream>>>(ei, cursor, csr);
    k_l1l2     <<<(BN + 255) / 256, blk, 0, stream>>>(dinv, xd, row, cnt, csr, W1, b1, W2, y2);
    k_agg2     <<<(BN * 8 + 255) / 256, blk, 0, stream>>>(y2, row, cnt, csr, z2);
    k_l3       <<<(BN + 255) / 256, blk, 0, stream>>>(dinv, z2, b2, W3, y3);
    k_agg3out  <<<(BN + 255) / 256, blk, 0, stream>>>(dinv, y3, row, cnt, csr, b3, out);
}

// Round 5
// 287.439 us; speedup vs baseline: 1.0295x; 1.0295x over previous
//
#include <hip/hip_runtime.h>
#include <math.h>

#define N_NODES 50000
#define N_EDGES 800000
#define BATCH   4
#define C1      64
#define C2      32
#define BN      (BATCH * N_NODES)
#define NBLK_N  ((N_NODES + 255) / 256)
#define NBLK_AGG ((N_NODES + 63) / 64)   // blocks per (batch,half) in k_agg2

// ---------------- CSR build ----------------

__global__ void k_zero(int* __restrict__ cnt, float* __restrict__ y3) {
    int t = blockIdx.x * 256 + threadIdx.x;
    if (t < N_NODES) cnt[t] = 0;
    if (t < BN) y3[t] = 0.0f;
}

// histogram of in-degree (dst)
__global__ void k_hist(const int* __restrict__ ei, int* __restrict__ cnt) {
    int e = blockIdx.x * 256 + threadIdx.x;
    if (e >= N_EDGES) return;
    atomicAdd(&cnt[ei[N_EDGES + e]], 1);
}

// single-block: per-residue (n&7) totals of cnt -> exclusive prefix -> cur8 bases
__global__ __launch_bounds__(1024) void k_bcur(const int* __restrict__ cnt,
                                               int* __restrict__ cur8) {
    __shared__ int buf[1024];
    int tid = threadIdx.x;
    int acc = 0;
    for (int i = tid; i < N_NODES; i += 1024) acc += cnt[i];  // i&7 == tid&7
    buf[tid] = acc;
    __syncthreads();
    for (int s = 512; s >= 8; s >>= 1) {
        if (tid < s) buf[tid] += buf[tid + s];   // s multiple of 8 -> residue preserved
        __syncthreads();
    }
    if (tid == 0) {
        int base = 0;
        for (int r = 0; r < 8; r++) { int t = buf[r]; cur8[r] = base; base += t; }
    }
}

// allocator (bucketed by n&7, per-bucket bump) + fused xd = x * dinv
__global__ __launch_bounds__(256) void k_alloc_xd(
        const int* __restrict__ cnt, const float* __restrict__ x,
        int* __restrict__ row, int* __restrict__ cursor, float* __restrict__ dinv,
        float* __restrict__ xd, int* __restrict__ cur8) {
    int t = blockIdx.x * 256 + threadIdx.x;

    if (blockIdx.x < NBLK_N) {   // allocator region (uniform per block)
        int lane = threadIdx.x & 63;
        int v = (t < N_NODES) ? cnt[t] : 0;
        // stride-8 segmented inclusive scan over the wave (residue = lane&7)
        int xs = v;
#pragma unroll
        for (int s = 8; s < 64; s <<= 1) {
            int y = __shfl_up(xs, s, 64);
            if (lane >= s) xs += y;
        }
        int base = 0;
        if (lane >= 56) base = atomicAdd(&cur8[lane & 7], xs);  // xs = residue total
        base = __shfl(base, 56 + (lane & 7), 64);
        if (t < N_NODES) {
            int r = base + (xs - v);
            row[t] = r;
            cursor[t] = r;
            dinv[t] = rsqrtf((float)(v + 1));   // +1 self-loop
        }
    }

    if (t < BN) {
        int n = t % N_NODES;
        float di = rsqrtf((float)(cnt[n] + 1));
        xd[t] = x[t] * di;
    }
}

// bucketed fill: block bid handles edges with (dst&7)==(bid&7) -> single-writer-XCD
__global__ void k_fill(const int* __restrict__ ei, int* __restrict__ cursor,
                       int* __restrict__ csr) {
    int bid = blockIdx.x;
    int r = bid & 7;
    int e = (bid >> 3) * 256 + threadIdx.x;
    if (e >= N_EDGES) return;
    int d = ei[N_EDGES + e];
    if ((d & 7) != r) return;
    int s = ei[e];
    int pos = atomicAdd(&cursor[d], 1);
    csr[pos] = s;
}

// ---------------- compute ----------------

// fused layer1 aggregation + dense 1->64 (relu) -> 64x32 matvec
// output split by channel halves: y2a = ch 0..15, y2b = ch 16..31 (each [BN][16])
__global__ __launch_bounds__(256) void k_l1l2(
        const float* __restrict__ dinv, const float* __restrict__ xd,
        const int* __restrict__ row, const int* __restrict__ cnt,
        const int* __restrict__ csr,
        const float* __restrict__ W1, const float* __restrict__ b1,
        const float* __restrict__ W2,
        float* __restrict__ y2a, float* __restrict__ y2b) {
    __shared__ float sW1[C1], sb1[C1], sW2[C1 * C2];
    int lt = threadIdx.x;
    for (int i = lt; i < C1; i += 256) { sW1[i] = W1[i]; sb1[i] = b1[i]; }
    for (int i = lt; i < C1 * C2; i += 256) sW2[i] = W2[i];
    __syncthreads();

    int t = blockIdx.x * 256 + lt;
    if (t >= BN) return;
    int n = t % N_NODES;
    int base = t - n;                 // b*N
    float di = dinv[n];

    float s = xd[t];                  // self-loop
    int r0 = row[n], r1 = r0 + cnt[n];
    int k = r0;
    for (; k + 1 < r1; k += 2) {
        int s0 = csr[k], s1 = csr[k + 1];
        s += xd[base + s0] + xd[base + s1];
    }
    if (k < r1) s += xd[base + csr[k]];
    float px = di * s;

    float acc[C2];
#pragma unroll
    for (int j = 0; j < C2; j++) acc[j] = 0.0f;

    for (int c = 0; c < C1; c++) {
        float h = fmaxf(px * sW1[c] + sb1[c], 0.0f);
        const float4* rw = (const float4*)&sW2[c * C2];
#pragma unroll
        for (int j4 = 0; j4 < C2 / 4; j4++) {
            float4 w = rw[j4];
            acc[4 * j4 + 0] += h * w.x;
            acc[4 * j4 + 1] += h * w.y;
            acc[4 * j4 + 2] += h * w.z;
            acc[4 * j4 + 3] += h * w.w;
        }
    }

    float4* ya = (float4*)&y2a[(size_t)t * 16];
    float4* yb = (float4*)&y2b[(size_t)t * 16];
#pragma unroll
    for (int j4 = 0; j4 < 4; j4++) {
        float4 v;
        v.x = acc[4 * j4 + 0] * di;
        v.y = acc[4 * j4 + 1] * di;
        v.z = acc[4 * j4 + 2] * di;
        v.w = acc[4 * j4 + 3] * di;
        ya[j4] = v;
        float4 w;
        w.x = acc[16 + 4 * j4 + 0] * di;
        w.y = acc[16 + 4 * j4 + 1] * di;
        w.z = acc[16 + 4 * j4 + 2] * di;
        w.w = acc[16 + 4 * j4 + 3] * di;
        yb[j4] = w;
    }
}

// layer-2 aggregation + fused layer-2 epilogue + layer-3 transform.
// XCD-affine: xcd=blk&7 -> batch=xcd>>1, half=xcd&1; per-XCD gather table is a
// contiguous 3.2 MB slice (fits 4 MiB L2). Quad of threads = one node (16 ch).
// Epilogue: partial dot with W3 over this half's channels, quad-reduce,
// atomicAdd into y3 (y3 = dinv * (relu(dinv*agg + b2) @ W3), summed over halves).
__global__ __launch_bounds__(256) void k_agg2(
        const float* __restrict__ y2a, const float* __restrict__ y2b,
        const int* __restrict__ row, const int* __restrict__ cnt,
        const int* __restrict__ csr,
        const float* __restrict__ dinv, const float* __restrict__ b2,
        const float* __restrict__ W3, float* __restrict__ y3) {
    int blk = blockIdx.x;
    int xcd = blk & 7;
    int half = xcd & 1;
    int batch = xcd >> 1;
    int sub = blk >> 3;
    int lt = threadIdx.x;
    int node = sub * 64 + (lt >> 2);
    if (node >= N_NODES) return;
    int q = lt & 3;

    const float4* Y = (const float4*)(half ? y2b : y2a);
    int bbase = batch * N_NODES;
    int idx = bbase + node;

    float4 a = Y[(size_t)idx * 4 + q];    // self
    int r0 = row[node], r1 = r0 + cnt[node];
    int k = r0;
    for (; k + 1 < r1; k += 2) {
        int s0 = csr[k], s1 = csr[k + 1];
        float4 v0 = Y[(size_t)(bbase + s0) * 4 + q];
        float4 v1 = Y[(size_t)(bbase + s1) * 4 + q];
        a.x += v0.x + v1.x; a.y += v0.y + v1.y;
        a.z += v0.z + v1.z; a.w += v0.w + v1.w;
    }
    if (k < r1) {
        float4 v = Y[(size_t)(bbase + csr[k]) * 4 + q];
        a.x += v.x; a.y += v.y; a.z += v.z; a.w += v.w;
    }

    float di = dinv[node];
    int c0 = half * 16 + q * 4;
    float p = fmaxf(di * a.x + b2[c0 + 0], 0.0f) * W3[c0 + 0]
            + fmaxf(di * a.y + b2[c0 + 1], 0.0f) * W3[c0 + 1]
            + fmaxf(di * a.z + b2[c0 + 2], 0.0f) * W3[c0 + 2]
            + fmaxf(di * a.w + b2[c0 + 3], 0.0f) * W3[c0 + 3];
    p += __shfl_xor(p, 1, 64);
    p += __shfl_xor(p, 2, 64);
    if (q == 0) atomicAdd(&y3[idx], di * p);
}

// layer-3 aggregation + sigmoid output
__global__ void k_agg3out(const float* __restrict__ dinv, const float* __restrict__ y3,
                          const int* __restrict__ row, const int* __restrict__ cnt,
                          const int* __restrict__ csr,
                          const float* __restrict__ b3, float* __restrict__ out) {
    int t = blockIdx.x * 256 + threadIdx.x;
    if (t >= BN) return;
    int n = t % N_NODES;
    int base = t - n;
    float a = y3[t];                  // self
    int r0 = row[n], r1 = r0 + cnt[n];
    int k = r0;
    for (; k + 1 < r1; k += 2) {
        int s0 = csr[k], s1 = csr[k + 1];
        a += y3[base + s0] + y3[base + s1];
    }
    if (k < r1) a += y3[base + csr[k]];
    float v = dinv[n] * a + b3[0];
    out[t] = 1.0f / (1.0f + expf(-v));
}

// ---------------- launch ----------------

extern "C" void kernel_launch(void* const* d_in, const int* in_sizes, int n_in,
                              void* d_out, int out_size, void* d_ws, size_t ws_size,
                              hipStream_t stream) {
    const float* x   = (const float*)d_in[0];
    const int*   ei  = (const int*)d_in[1];
    const float* W1  = (const float*)d_in[2];
    const float* b1  = (const float*)d_in[3];
    const float* W2  = (const float*)d_in[4];
    const float* b2  = (const float*)d_in[5];
    const float* W3  = (const float*)d_in[6];
    const float* b3  = (const float*)d_in[7];
    float* out = (float*)d_out;

    char* ws = (char*)d_ws;
    size_t off = 0;
    auto carve = [&](size_t bytes) {
        void* p = ws + off;
        off = (off + bytes + 255) & ~(size_t)255;
        return p;
    };
    int*   cnt    = (int*)  carve(N_NODES * 4);
    int*   row    = (int*)  carve(N_NODES * 4);
    int*   cursor = (int*)  carve(N_NODES * 4);
    float* dinv   = (float*)carve(N_NODES * 4);
    int*   csr    = (int*)  carve(N_EDGES * 4);
    float* xd     = (float*)carve(BN * 4);
    float* y2a    = (float*)carve((size_t)BN * 16 * 4);
    float* y2b    = (float*)carve((size_t)BN * 16 * 4);
    float* y3     = (float*)carve(BN * 4);
    int*   cur8   = (int*)  carve(8 * 4);

    dim3 blk(256);

    k_zero     <<<(BN + 255) / 256, blk, 0, stream>>>(cnt, y3);
    k_hist     <<<(N_EDGES + 255) / 256, blk, 0, stream>>>(ei, cnt);
    k_bcur     <<<1, 1024, 0, stream>>>(cnt, cur8);
    k_alloc_xd <<<(BN + 255) / 256, blk, 0, stream>>>(cnt, x, row, cursor, dinv, xd, cur8);
    k_fill     <<<8 * ((N_EDGES + 255) / 256), blk, 0, stream>>>(ei, cursor, csr);
    k_l1l2     <<<(BN + 255) / 256, blk, 0, stream>>>(dinv, xd, row, cnt, csr, W1, b1, W2, y2a, y2b);
    k_agg2     <<<8 * NBLK_AGG, blk, 0, stream>>>(y2a, y2b, row, cnt, csr, dinv, b2, W3, y3);
    k_agg3out  <<<(BN + 255) / 256, blk, 0, stream>>>(dinv, y3, row, cnt, csr, b3, out);
}

// Round 6
// 274.996 us; speedup vs baseline: 1.0761x; 1.0452x over previous
//
#include <hip/hip_runtime.h>
#include <math.h>

#define N_NODES 50000
#define N_EDGES 800000
#define BATCH   4
#define C1      64
#define C2      32
#define BN      (BATCH * N_NODES)
#define NBLK_N  ((N_NODES + 255) / 256)
#define NBLK_AGG ((N_NODES + 63) / 64)   // blocks per (batch,half) in k_agg2

// ---------------- CSR build ----------------

__global__ void k_zero(int* __restrict__ cnt, float* __restrict__ y3) {
    int t = blockIdx.x * 256 + threadIdx.x;
    if (t < N_NODES) cnt[t] = 0;
    if (t < BN) y3[t] = 0.0f;
}

// histogram of in-degree (dst)
__global__ void k_hist(const int* __restrict__ ei, int* __restrict__ cnt) {
    int e = blockIdx.x * 256 + threadIdx.x;
    if (e >= N_EDGES) return;
    atomicAdd(&cnt[ei[N_EDGES + e]], 1);
}

// single-block: per-residue (n&7) totals of cnt -> exclusive prefix -> cur8 bases
__global__ __launch_bounds__(1024) void k_bcur(const int* __restrict__ cnt,
                                               int* __restrict__ cur8) {
    __shared__ int buf[1024];
    int tid = threadIdx.x;
    int acc = 0;
    for (int i = tid; i < N_NODES; i += 1024) acc += cnt[i];  // i&7 == tid&7
    buf[tid] = acc;
    __syncthreads();
    for (int s = 512; s >= 8; s >>= 1) {
        if (tid < s) buf[tid] += buf[tid + s];   // s multiple of 8 -> residue preserved
        __syncthreads();
    }
    if (tid == 0) {
        int base = 0;
        for (int r = 0; r < 8; r++) { int t = buf[r]; cur8[r] = base; base += t; }
    }
}

// allocator (bucketed by n&7, per-bucket bump) + fused xd = x * dinv
__global__ __launch_bounds__(256) void k_alloc_xd(
        const int* __restrict__ cnt, const float* __restrict__ x,
        int* __restrict__ row, int* __restrict__ cursor, float* __restrict__ dinv,
        float* __restrict__ xd, int* __restrict__ cur8) {
    int t = blockIdx.x * 256 + threadIdx.x;

    if (blockIdx.x < NBLK_N) {   // allocator region (uniform per block)
        int lane = threadIdx.x & 63;
        int v = (t < N_NODES) ? cnt[t] : 0;
        // stride-8 segmented inclusive scan over the wave (residue = lane&7)
        int xs = v;
#pragma unroll
        for (int s = 8; s < 64; s <<= 1) {
            int y = __shfl_up(xs, s, 64);
            if (lane >= s) xs += y;
        }
        int base = 0;
        if (lane >= 56) base = atomicAdd(&cur8[lane & 7], xs);  // xs = residue total
        base = __shfl(base, 56 + (lane & 7), 64);
        if (t < N_NODES) {
            int r = base + (xs - v);
            row[t] = r;
            cursor[t] = r;
            dinv[t] = rsqrtf((float)(v + 1));   // +1 self-loop
        }
    }

    if (t < BN) {
        int n = t % N_NODES;
        float di = rsqrtf((float)(cnt[n] + 1));
        xd[t] = x[t] * di;
    }
}

// bucketed fill: block bid handles edges with (dst&7)==(bid&7) -> single-writer-XCD
__global__ void k_fill(const int* __restrict__ ei, int* __restrict__ cursor,
                       int* __restrict__ csr) {
    int bid = blockIdx.x;
    int r = bid & 7;
    int e = (bid >> 3) * 256 + threadIdx.x;
    if (e >= N_EDGES) return;
    int d = ei[N_EDGES + e];
    if ((d & 7) != r) return;
    int s = ei[e];
    int pos = atomicAdd(&cursor[d], 1);
    csr[pos] = s;
}

// ---------------- compute ----------------

// fused layer1 aggregation + dense 1->64 (relu) -> 64x32 matvec
// output split by channel halves: y2a = ch 0..15, y2b = ch 16..31 (each [BN][16])
__global__ __launch_bounds__(256) void k_l1l2(
        const float* __restrict__ dinv, const float* __restrict__ xd,
        const int* __restrict__ row, const int* __restrict__ cnt,
        const int* __restrict__ csr,
        const float* __restrict__ W1, const float* __restrict__ b1,
        const float* __restrict__ W2,
        float* __restrict__ y2a, float* __restrict__ y2b) {
    __shared__ float sW1[C1], sb1[C1], sW2[C1 * C2];
    int lt = threadIdx.x;
    for (int i = lt; i < C1; i += 256) { sW1[i] = W1[i]; sb1[i] = b1[i]; }
    for (int i = lt; i < C1 * C2; i += 256) sW2[i] = W2[i];
    __syncthreads();

    int t = blockIdx.x * 256 + lt;
    if (t >= BN) return;
    int n = t % N_NODES;
    int base = t - n;                 // b*N
    float di = dinv[n];

    float s = xd[t];                  // self-loop
    int r0 = row[n], r1 = r0 + cnt[n];
    int k = r0;
    // unroll-8: 8 independent idx loads, then 8 independent gathers (MLP)
    for (; k + 8 <= r1; k += 8) {
        int i0 = csr[k + 0], i1 = csr[k + 1], i2 = csr[k + 2], i3 = csr[k + 3];
        int i4 = csr[k + 4], i5 = csr[k + 5], i6 = csr[k + 6], i7 = csr[k + 7];
        float g0 = xd[base + i0], g1 = xd[base + i1];
        float g2 = xd[base + i2], g3 = xd[base + i3];
        float g4 = xd[base + i4], g5 = xd[base + i5];
        float g6 = xd[base + i6], g7 = xd[base + i7];
        s += ((g0 + g1) + (g2 + g3)) + ((g4 + g5) + (g6 + g7));
    }
    for (; k < r1; k++) s += xd[base + csr[k]];
    float px = di * s;

    float acc[C2];
#pragma unroll
    for (int j = 0; j < C2; j++) acc[j] = 0.0f;

    for (int c = 0; c < C1; c++) {
        float h = fmaxf(px * sW1[c] + sb1[c], 0.0f);
        const float4* rw = (const float4*)&sW2[c * C2];
#pragma unroll
        for (int j4 = 0; j4 < C2 / 4; j4++) {
            float4 w = rw[j4];
            acc[4 * j4 + 0] += h * w.x;
            acc[4 * j4 + 1] += h * w.y;
            acc[4 * j4 + 2] += h * w.z;
            acc[4 * j4 + 3] += h * w.w;
        }
    }

    float4* ya = (float4*)&y2a[(size_t)t * 16];
    float4* yb = (float4*)&y2b[(size_t)t * 16];
#pragma unroll
    for (int j4 = 0; j4 < 4; j4++) {
        float4 v;
        v.x = acc[4 * j4 + 0] * di;
        v.y = acc[4 * j4 + 1] * di;
        v.z = acc[4 * j4 + 2] * di;
        v.w = acc[4 * j4 + 3] * di;
        ya[j4] = v;
        float4 w;
        w.x = acc[16 + 4 * j4 + 0] * di;
        w.y = acc[16 + 4 * j4 + 1] * di;
        w.z = acc[16 + 4 * j4 + 2] * di;
        w.w = acc[16 + 4 * j4 + 3] * di;
        yb[j4] = w;
    }
}

// layer-2 aggregation + fused layer-2 epilogue + layer-3 transform.
// XCD-affine: xcd=blk&7 -> batch=xcd>>1, half=xcd&1; per-XCD gather table is a
// contiguous 3.2 MB slice (fits 4 MiB L2). Quad of threads = one node (16 ch).
__global__ __launch_bounds__(256) void k_agg2(
        const float* __restrict__ y2a, const float* __restrict__ y2b,
        const int* __restrict__ row, const int* __restrict__ cnt,
        const int* __restrict__ csr,
        const float* __restrict__ dinv, const float* __restrict__ b2,
        const float* __restrict__ W3, float* __restrict__ y3) {
    int blk = blockIdx.x;
    int xcd = blk & 7;
    int half = xcd & 1;
    int batch = xcd >> 1;
    int sub = blk >> 3;
    int lt = threadIdx.x;
    int node = sub * 64 + (lt >> 2);
    if (node >= N_NODES) return;
    int q = lt & 3;

    const float4* Y = (const float4*)(half ? y2b : y2a);
    int bbase = batch * N_NODES;
    int idx = bbase + node;

    float4 a = Y[(size_t)idx * 4 + q];    // self
    int r0 = row[node], r1 = r0 + cnt[node];
    int k = r0;
    // unroll-8: 8 independent idx loads, then 8 independent float4 gathers
    for (; k + 8 <= r1; k += 8) {
        int i0 = csr[k + 0], i1 = csr[k + 1], i2 = csr[k + 2], i3 = csr[k + 3];
        int i4 = csr[k + 4], i5 = csr[k + 5], i6 = csr[k + 6], i7 = csr[k + 7];
        float4 v0 = Y[(size_t)(bbase + i0) * 4 + q];
        float4 v1 = Y[(size_t)(bbase + i1) * 4 + q];
        float4 v2 = Y[(size_t)(bbase + i2) * 4 + q];
        float4 v3 = Y[(size_t)(bbase + i3) * 4 + q];
        float4 v4 = Y[(size_t)(bbase + i4) * 4 + q];
        float4 v5 = Y[(size_t)(bbase + i5) * 4 + q];
        float4 v6 = Y[(size_t)(bbase + i6) * 4 + q];
        float4 v7 = Y[(size_t)(bbase + i7) * 4 + q];
        a.x += ((v0.x + v1.x) + (v2.x + v3.x)) + ((v4.x + v5.x) + (v6.x + v7.x));
        a.y += ((v0.y + v1.y) + (v2.y + v3.y)) + ((v4.y + v5.y) + (v6.y + v7.y));
        a.z += ((v0.z + v1.z) + (v2.z + v3.z)) + ((v4.z + v5.z) + (v6.z + v7.z));
        a.w += ((v0.w + v1.w) + (v2.w + v3.w)) + ((v4.w + v5.w) + (v6.w + v7.w));
    }
    for (; k < r1; k++) {
        float4 v = Y[(size_t)(bbase + csr[k]) * 4 + q];
        a.x += v.x; a.y += v.y; a.z += v.z; a.w += v.w;
    }

    float di = dinv[node];
    int c0 = half * 16 + q * 4;
    float p = fmaxf(di * a.x + b2[c0 + 0], 0.0f) * W3[c0 + 0]
            + fmaxf(di * a.y + b2[c0 + 1], 0.0f) * W3[c0 + 1]
            + fmaxf(di * a.z + b2[c0 + 2], 0.0f) * W3[c0 + 2]
            + fmaxf(di * a.w + b2[c0 + 3], 0.0f) * W3[c0 + 3];
    p += __shfl_xor(p, 1, 64);
    p += __shfl_xor(p, 2, 64);
    if (q == 0) atomicAdd(&y3[idx], di * p);
}

// layer-3 aggregation + sigmoid output
__global__ void k_agg3out(const float* __restrict__ dinv, const float* __restrict__ y3,
                          const int* __restrict__ row, const int* __restrict__ cnt,
                          const int* __restrict__ csr,
                          const float* __restrict__ b3, float* __restrict__ out) {
    int t = blockIdx.x * 256 + threadIdx.x;
    if (t >= BN) return;
    int n = t % N_NODES;
    int base = t - n;
    float a = y3[t];                  // self
    int r0 = row[n], r1 = r0 + cnt[n];
    int k = r0;
    for (; k + 8 <= r1; k += 8) {
        int i0 = csr[k + 0], i1 = csr[k + 1], i2 = csr[k + 2], i3 = csr[k + 3];
        int i4 = csr[k + 4], i5 = csr[k + 5], i6 = csr[k + 6], i7 = csr[k + 7];
        float g0 = y3[base + i0], g1 = y3[base + i1];
        float g2 = y3[base + i2], g3 = y3[base + i3];
        float g4 = y3[base + i4], g5 = y3[base + i5];
        float g6 = y3[base + i6], g7 = y3[base + i7];
        a += ((g0 + g1) + (g2 + g3)) + ((g4 + g5) + (g6 + g7));
    }
    for (; k < r1; k++) a += y3[base + csr[k]];
    float v = dinv[n] * a + b3[0];
    out[t] = 1.0f / (1.0f + expf(-v));
}

// ---------------- launch ----------------

extern "C" void kernel_launch(void* const* d_in, const int* in_sizes, int n_in,
                              void* d_out, int out_size, void* d_ws, size_t ws_size,
                              hipStream_t stream) {
    const float* x   = (const float*)d_in[0];
    const int*   ei  = (const int*)d_in[1];
    const float* W1  = (const float*)d_in[2];
    const float* b1  = (const float*)d_in[3];
    const float* W2  = (const float*)d_in[4];
    const float* b2  = (const float*)d_in[5];
    const float* W3  = (const float*)d_in[6];
    const float* b3  = (const float*)d_in[7];
    float* out = (float*)d_out;

    char* ws = (char*)d_ws;
    size_t off = 0;
    auto carve = [&](size_t bytes) {
        void* p = ws + off;
        off = (off + bytes + 255) & ~(size_t)255;
        return p;
    };
    int*   cnt    = (int*)  carve(N_NODES * 4);
    int*   row    = (int*)  carve(N_NODES * 4);
    int*   cursor = (int*)  carve(N_NODES * 4);
    float* dinv   = (float*)carve(N_NODES * 4);
    int*   csr    = (int*)  carve(N_EDGES * 4);
    float* xd     = (float*)carve(BN * 4);
    float* y2a    = (float*)carve((size_t)BN * 16 * 4);
    float* y2b    = (float*)carve((size_t)BN * 16 * 4);
    float* y3     = (float*)carve(BN * 4);
    int*   cur8   = (int*)  carve(8 * 4);

    dim3 blk(256);

    k_zero     <<<(BN + 255) / 256, blk, 0, stream>>>(cnt, y3);
    k_hist     <<<(N_EDGES + 255) / 256, blk, 0, stream>>>(ei, cnt);
    k_bcur     <<<1, 1024, 0, stream>>>(cnt, cur8);
    k_alloc_xd <<<(BN + 255) / 256, blk, 0, stream>>>(cnt, x, row, cursor, dinv, xd, cur8);
    k_fill     <<<8 * ((N_EDGES + 255) / 256), blk, 0, stream>>>(ei, cursor, csr);
    k_l1l2     <<<(BN + 255) / 256, blk, 0, stream>>>(dinv, xd, row, cnt, csr, W1, b1, W2, y2a, y2b);
    k_agg2     <<<8 * NBLK_AGG, blk, 0, stream>>>(y2a, y2b, row, cnt, csr, dinv, b2, W3, y3);
    k_agg3out  <<<(BN + 255) / 256, blk, 0, stream>>>(dinv, y3, row, cnt, csr, b3, out);
}

// Round 7
// 254.978 us; speedup vs baseline: 1.1606x; 1.0785x over previous
//
#include <hip/hip_runtime.h>
#include <math.h>

#define N_NODES 50000
#define N_EDGES 800000
#define BATCH   4
#define C1      64
#define C2      32
#define BN      (BATCH * N_NODES)
#define NBLK_N  ((N_NODES + 255) / 256)
#define NBLK_Q  ((N_NODES + 63) / 64)    // blocks at 4 lanes/node

// ---------------- CSR build ----------------

__global__ void k_zero(int* __restrict__ cnt, float* __restrict__ y3t) {
    int t = blockIdx.x * 256 + threadIdx.x;
    if (t < N_NODES) cnt[t] = 0;
    if (t < BN) y3t[t] = 0.0f;        // y3t = [n][4 batches]
}

// histogram of in-degree (dst)
__global__ void k_hist(const int* __restrict__ ei, int* __restrict__ cnt) {
    int e = blockIdx.x * 256 + threadIdx.x;
    if (e >= N_EDGES) return;
    atomicAdd(&cnt[ei[N_EDGES + e]], 1);
}

// single-block: per-residue (n&7) totals of cnt -> exclusive prefix -> cur8 bases
__global__ __launch_bounds__(1024) void k_bcur(const int* __restrict__ cnt,
                                               int* __restrict__ cur8) {
    __shared__ int buf[1024];
    int tid = threadIdx.x;
    int acc = 0;
    for (int i = tid; i < N_NODES; i += 1024) acc += cnt[i];  // i&7 == tid&7
    buf[tid] = acc;
    __syncthreads();
    for (int s = 512; s >= 8; s >>= 1) {
        if (tid < s) buf[tid] += buf[tid + s];   // s multiple of 8 -> residue preserved
        __syncthreads();
    }
    if (tid == 0) {
        int base = 0;
        for (int r = 0; r < 8; r++) { int t = buf[r]; cur8[r] = base; base += t; }
    }
}

// allocator (bucketed by n&7, per-bucket bump) + fused xd4 = x * dinv (batch-transposed)
__global__ __launch_bounds__(256) void k_alloc_xd(
        const int* __restrict__ cnt, const float* __restrict__ x,
        int* __restrict__ row, int* __restrict__ cursor, float* __restrict__ dinv,
        float4* __restrict__ xd4, int* __restrict__ cur8) {
    int t = blockIdx.x * 256 + threadIdx.x;
    int lane = threadIdx.x & 63;
    int v = (t < N_NODES) ? cnt[t] : 0;
    // stride-8 segmented inclusive scan over the wave (residue = lane&7)
    int xs = v;
#pragma unroll
    for (int s = 8; s < 64; s <<= 1) {
        int y = __shfl_up(xs, s, 64);
        if (lane >= s) xs += y;
    }
    int base = 0;
    if (lane >= 56) base = atomicAdd(&cur8[lane & 7], xs);  // xs = residue total
    base = __shfl(base, 56 + (lane & 7), 64);
    if (t < N_NODES) {
        int r = base + (xs - v);
        row[t] = r;
        cursor[t] = r;
        float di = rsqrtf((float)(v + 1));   // +1 self-loop
        dinv[t] = di;
        float4 w;
        w.x = x[t] * di;
        w.y = x[N_NODES + t] * di;
        w.z = x[2 * N_NODES + t] * di;
        w.w = x[3 * N_NODES + t] * di;
        xd4[t] = w;
    }
}

// bucketed fill: block bid handles edges with (dst&7)==(bid&7) -> single-writer-XCD
__global__ void k_fill(const int* __restrict__ ei, int* __restrict__ cursor,
                       int* __restrict__ csr) {
    int bid = blockIdx.x;
    int r = bid & 7;
    int e = (bid >> 3) * 256 + threadIdx.x;
    if (e >= N_EDGES) return;
    int d = ei[N_EDGES + e];
    if ((d & 7) != r) return;
    int s = ei[e];
    int pos = atomicAdd(&cursor[d], 1);
    csr[pos] = s;
}

// ---------------- compute ----------------

// layer-1 aggregation, batch-shared: px4[n] = dinv[n] * (xd4[n] + sum_in xd4[s])
// 4 lanes per node, each lane strides 4 through the row, unroll-4 -> 4 outstanding float4
__global__ __launch_bounds__(256) void k_agg1(
        const float* __restrict__ dinv, const float4* __restrict__ xd4,
        const int* __restrict__ row, const int* __restrict__ cnt,
        const int* __restrict__ csr, float4* __restrict__ px4) {
    int lt = threadIdx.x;
    int node = blockIdx.x * 64 + (lt >> 2);
    if (node >= N_NODES) return;
    int q = lt & 3;

    float4 a = make_float4(0.f, 0.f, 0.f, 0.f);
    if (q == 0) a = xd4[node];        // self
    int r0 = row[node], r1 = r0 + cnt[node];
    int k = r0 + q;
    for (; k + 12 < r1; k += 16) {
        int i0 = csr[k], i1 = csr[k + 4], i2 = csr[k + 8], i3 = csr[k + 12];
        float4 g0 = xd4[i0], g1 = xd4[i1], g2 = xd4[i2], g3 = xd4[i3];
        a.x += (g0.x + g1.x) + (g2.x + g3.x);
        a.y += (g0.y + g1.y) + (g2.y + g3.y);
        a.z += (g0.z + g1.z) + (g2.z + g3.z);
        a.w += (g0.w + g1.w) + (g2.w + g3.w);
    }
    for (; k < r1; k += 4) {
        float4 g = xd4[csr[k]];
        a.x += g.x; a.y += g.y; a.z += g.z; a.w += g.w;
    }
    // quad reduce
#pragma unroll
    for (int m = 1; m <= 2; m <<= 1) {
        a.x += __shfl_xor(a.x, m, 64);
        a.y += __shfl_xor(a.y, m, 64);
        a.z += __shfl_xor(a.z, m, 64);
        a.w += __shfl_xor(a.w, m, 64);
    }
    if (q == 0) {
        float di = dinv[node];
        a.x *= di; a.y *= di; a.z *= di; a.w *= di;
        px4[node] = a;
    }
}

// dense per (b,n): h1 = relu(px*W1+b1); y2 = dinv * (h1@W2), split channel halves
__global__ __launch_bounds__(256) void k_mv(
        const float* __restrict__ dinv, const float4* __restrict__ px4,
        const float* __restrict__ W1, const float* __restrict__ b1,
        const float* __restrict__ W2,
        float* __restrict__ y2a, float* __restrict__ y2b) {
    __shared__ float sW1[C1], sb1[C1], sW2[C1 * C2];
    int lt = threadIdx.x;
    for (int i = lt; i < C1; i += 256) { sW1[i] = W1[i]; sb1[i] = b1[i]; }
    for (int i = lt; i < C1 * C2; i += 256) sW2[i] = W2[i];
    __syncthreads();

    int t = blockIdx.x * 256 + lt;
    if (t >= BN) return;
    int n = t % N_NODES;
    int b = t / N_NODES;
    float di = dinv[n];
    float px = ((const float*)px4)[n * 4 + b];

    float acc[C2];
#pragma unroll
    for (int j = 0; j < C2; j++) acc[j] = 0.0f;

    for (int c = 0; c < C1; c++) {
        float h = fmaxf(px * sW1[c] + sb1[c], 0.0f);
        const float4* rw = (const float4*)&sW2[c * C2];
#pragma unroll
        for (int j4 = 0; j4 < C2 / 4; j4++) {
            float4 w = rw[j4];
            acc[4 * j4 + 0] += h * w.x;
            acc[4 * j4 + 1] += h * w.y;
            acc[4 * j4 + 2] += h * w.z;
            acc[4 * j4 + 3] += h * w.w;
        }
    }

    float4* ya = (float4*)&y2a[(size_t)t * 16];
    float4* yb = (float4*)&y2b[(size_t)t * 16];
#pragma unroll
    for (int j4 = 0; j4 < 4; j4++) {
        float4 v;
        v.x = acc[4 * j4 + 0] * di;
        v.y = acc[4 * j4 + 1] * di;
        v.z = acc[4 * j4 + 2] * di;
        v.w = acc[4 * j4 + 3] * di;
        ya[j4] = v;
        float4 w;
        w.x = acc[16 + 4 * j4 + 0] * di;
        w.y = acc[16 + 4 * j4 + 1] * di;
        w.z = acc[16 + 4 * j4 + 2] * di;
        w.w = acc[16 + 4 * j4 + 3] * di;
        yb[j4] = w;
    }
}

// layer-2 aggregation + fused epilogue + layer-3 transform (XCD-affine, L2-resident)
__global__ __launch_bounds__(256) void k_agg2(
        const float* __restrict__ y2a, const float* __restrict__ y2b,
        const int* __restrict__ row, const int* __restrict__ cnt,
        const int* __restrict__ csr,
        const float* __restrict__ dinv, const float* __restrict__ b2,
        const float* __restrict__ W3, float* __restrict__ y3t) {
    int blk = blockIdx.x;
    int xcd = blk & 7;
    int half = xcd & 1;
    int batch = xcd >> 1;
    int sub = blk >> 3;
    int lt = threadIdx.x;
    int node = sub * 64 + (lt >> 2);
    if (node >= N_NODES) return;
    int q = lt & 3;

    const float4* Y = (const float4*)(half ? y2b : y2a);
    int bbase = batch * N_NODES;
    int idx = bbase + node;

    float4 a = Y[(size_t)idx * 4 + q];    // self
    int r0 = row[node], r1 = r0 + cnt[node];
    int k = r0;
    for (; k + 8 <= r1; k += 8) {
        int i0 = csr[k + 0], i1 = csr[k + 1], i2 = csr[k + 2], i3 = csr[k + 3];
        int i4 = csr[k + 4], i5 = csr[k + 5], i6 = csr[k + 6], i7 = csr[k + 7];
        float4 v0 = Y[(size_t)(bbase + i0) * 4 + q];
        float4 v1 = Y[(size_t)(bbase + i1) * 4 + q];
        float4 v2 = Y[(size_t)(bbase + i2) * 4 + q];
        float4 v3 = Y[(size_t)(bbase + i3) * 4 + q];
        float4 v4 = Y[(size_t)(bbase + i4) * 4 + q];
        float4 v5 = Y[(size_t)(bbase + i5) * 4 + q];
        float4 v6 = Y[(size_t)(bbase + i6) * 4 + q];
        float4 v7 = Y[(size_t)(bbase + i7) * 4 + q];
        a.x += ((v0.x + v1.x) + (v2.x + v3.x)) + ((v4.x + v5.x) + (v6.x + v7.x));
        a.y += ((v0.y + v1.y) + (v2.y + v3.y)) + ((v4.y + v5.y) + (v6.y + v7.y));
        a.z += ((v0.z + v1.z) + (v2.z + v3.z)) + ((v4.z + v5.z) + (v6.z + v7.z));
        a.w += ((v0.w + v1.w) + (v2.w + v3.w)) + ((v4.w + v5.w) + (v6.w + v7.w));
    }
    for (; k < r1; k++) {
        float4 v = Y[(size_t)(bbase + csr[k]) * 4 + q];
        a.x += v.x; a.y += v.y; a.z += v.z; a.w += v.w;
    }

    float di = dinv[node];
    int c0 = half * 16 + q * 4;
    float p = fmaxf(di * a.x + b2[c0 + 0], 0.0f) * W3[c0 + 0]
            + fmaxf(di * a.y + b2[c0 + 1], 0.0f) * W3[c0 + 1]
            + fmaxf(di * a.z + b2[c0 + 2], 0.0f) * W3[c0 + 2]
            + fmaxf(di * a.w + b2[c0 + 3], 0.0f) * W3[c0 + 3];
    p += __shfl_xor(p, 1, 64);
    p += __shfl_xor(p, 2, 64);
    if (q == 0) atomicAdd(&y3t[node * 4 + batch], di * p);
}

// layer-3 aggregation + sigmoid, batch-shared float4 gathers (4 lanes/node)
__global__ __launch_bounds__(256) void k_agg3(
        const float* __restrict__ dinv, const float4* __restrict__ y3t,
        const int* __restrict__ row, const int* __restrict__ cnt,
        const int* __restrict__ csr,
        const float* __restrict__ b3, float* __restrict__ out) {
    int lt = threadIdx.x;
    int node = blockIdx.x * 64 + (lt >> 2);
    if (node >= N_NODES) return;
    int q = lt & 3;

    float4 a = make_float4(0.f, 0.f, 0.f, 0.f);
    if (q == 0) a = y3t[node];        // self
    int r0 = row[node], r1 = r0 + cnt[node];
    int k = r0 + q;
    for (; k + 12 < r1; k += 16) {
        int i0 = csr[k], i1 = csr[k + 4], i2 = csr[k + 8], i3 = csr[k + 12];
        float4 g0 = y3t[i0], g1 = y3t[i1], g2 = y3t[i2], g3 = y3t[i3];
        a.x += (g0.x + g1.x) + (g2.x + g3.x);
        a.y += (g0.y + g1.y) + (g2.y + g3.y);
        a.z += (g0.z + g1.z) + (g2.z + g3.z);
        a.w += (g0.w + g1.w) + (g2.w + g3.w);
    }
    for (; k < r1; k += 4) {
        float4 g = y3t[csr[k]];
        a.x += g.x; a.y += g.y; a.z += g.z; a.w += g.w;
    }
#pragma unroll
    for (int m = 1; m <= 2; m <<= 1) {
        a.x += __shfl_xor(a.x, m, 64);
        a.y += __shfl_xor(a.y, m, 64);
        a.z += __shfl_xor(a.z, m, 64);
        a.w += __shfl_xor(a.w, m, 64);
    }
    if (q == 0) {
        float di = dinv[node];
        float bb = b3[0];
        out[0 * N_NODES + node] = 1.0f / (1.0f + expf(-(di * a.x + bb)));
        out[1 * N_NODES + node] = 1.0f / (1.0f + expf(-(di * a.y + bb)));
        out[2 * N_NODES + node] = 1.0f / (1.0f + expf(-(di * a.z + bb)));
        out[3 * N_NODES + node] = 1.0f / (1.0f + expf(-(di * a.w + bb)));
    }
}

// ---------------- launch ----------------

extern "C" void kernel_launch(void* const* d_in, const int* in_sizes, int n_in,
                              void* d_out, int out_size, void* d_ws, size_t ws_size,
                              hipStream_t stream) {
    const float* x   = (const float*)d_in[0];
    const int*   ei  = (const int*)d_in[1];
    const float* W1  = (const float*)d_in[2];
    const float* b1  = (const float*)d_in[3];
    const float* W2  = (const float*)d_in[4];
    const float* b2  = (const float*)d_in[5];
    const float* W3  = (const float*)d_in[6];
    const float* b3  = (const float*)d_in[7];
    float* out = (float*)d_out;

    char* ws = (char*)d_ws;
    size_t off = 0;
    auto carve = [&](size_t bytes) {
        void* p = ws + off;
        off = (off + bytes + 255) & ~(size_t)255;
        return p;
    };
    int*    cnt    = (int*)   carve(N_NODES * 4);
    int*    row    = (int*)   carve(N_NODES * 4);
    int*    cursor = (int*)   carve(N_NODES * 4);
    float*  dinv   = (float*) carve(N_NODES * 4);
    int*    csr    = (int*)   carve(N_EDGES * 4);
    float4* xd4    = (float4*)carve((size_t)N_NODES * 16);
    float4* px4    = (float4*)carve((size_t)N_NODES * 16);
    float*  y2a    = (float*) carve((size_t)BN * 16 * 4);
    float*  y2b    = (float*) carve((size_t)BN * 16 * 4);
    float*  y3t    = (float*) carve((size_t)N_NODES * 16);
    int*    cur8   = (int*)   carve(8 * 4);

    dim3 blk(256);

    k_zero     <<<(BN + 255) / 256, blk, 0, stream>>>(cnt, y3t);
    k_hist     <<<(N_EDGES + 255) / 256, blk, 0, stream>>>(ei, cnt);
    k_bcur     <<<1, 1024, 0, stream>>>(cnt, cur8);
    k_alloc_xd <<<NBLK_N, blk, 0, stream>>>(cnt, x, row, cursor, dinv, xd4, cur8);
    k_fill     <<<8 * ((N_EDGES + 255) / 256), blk, 0, stream>>>(ei, cursor, csr);
    k_agg1     <<<NBLK_Q, blk, 0, stream>>>(dinv, xd4, row, cnt, csr, px4);
    k_mv       <<<(BN + 255) / 256, blk, 0, stream>>>(dinv, px4, W1, b1, W2, y2a, y2b);
    k_agg2     <<<8 * NBLK_Q, blk, 0, stream>>>(y2a, y2b, row, cnt, csr, dinv, b2, W3, y3t);
    k_agg3     <<<NBLK_Q, blk, 0, stream>>>(dinv, (const float4*)y3t, row, cnt, csr, b3, out);
}

// Round 8
// 253.241 us; speedup vs baseline: 1.1685x; 1.0069x over previous
//
#include <hip/hip_runtime.h>
#include <math.h>

#define N_NODES 50000
#define N_EDGES 800000
#define BATCH   4
#define C1      64
#define C2      32
#define BN      (BATCH * N_NODES)
#define NBLK_N  ((N_NODES + 255) / 256)
#define NBLK_Q  ((N_NODES + 63) / 64)    // blocks at 4 lanes/node

// ---------------- CSR build ----------------

__global__ void k_zero(int* __restrict__ cnt) {
    int t = blockIdx.x * 256 + threadIdx.x;
    if (t < N_NODES) cnt[t] = 0;
}

// histogram of in-degree (dst)
__global__ void k_hist(const int* __restrict__ ei, int* __restrict__ cnt) {
    int e = blockIdx.x * 256 + threadIdx.x;
    if (e >= N_EDGES) return;
    atomicAdd(&cnt[ei[N_EDGES + e]], 1);
}

// single-block: per-residue (n&7) totals of cnt -> exclusive prefix -> cur8 bases
__global__ __launch_bounds__(1024) void k_bcur(const int* __restrict__ cnt,
                                               int* __restrict__ cur8) {
    __shared__ int buf[1024];
    int tid = threadIdx.x;
    int acc = 0;
    for (int i = tid; i < N_NODES; i += 1024) acc += cnt[i];  // i&7 == tid&7
    buf[tid] = acc;
    __syncthreads();
    for (int s = 512; s >= 8; s >>= 1) {
        if (tid < s) buf[tid] += buf[tid + s];   // s multiple of 8 -> residue preserved
        __syncthreads();
    }
    if (tid == 0) {
        int base = 0;
        for (int r = 0; r < 8; r++) { int t = buf[r]; cur8[r] = base; base += t; }
    }
}

// allocator (bucketed by n&7, per-bucket bump) + fused xd4 = x*dinv + y3t zero
__global__ __launch_bounds__(256) void k_alloc_xd(
        const int* __restrict__ cnt, const float* __restrict__ x,
        int* __restrict__ row, int* __restrict__ cursor, float* __restrict__ dinv,
        float4* __restrict__ xd4, float4* __restrict__ y3t4, int* __restrict__ cur8) {
    int t = blockIdx.x * 256 + threadIdx.x;
    int lane = threadIdx.x & 63;
    int v = (t < N_NODES) ? cnt[t] : 0;
    // stride-8 segmented inclusive scan over the wave (residue = lane&7)
    int xs = v;
#pragma unroll
    for (int s = 8; s < 64; s <<= 1) {
        int y = __shfl_up(xs, s, 64);
        if (lane >= s) xs += y;
    }
    int base = 0;
    if (lane >= 56) base = atomicAdd(&cur8[lane & 7], xs);  // xs = residue total
    base = __shfl(base, 56 + (lane & 7), 64);
    if (t < N_NODES) {
        int r = base + (xs - v);
        row[t] = r;
        cursor[t] = r;
        float di = rsqrtf((float)(v + 1));   // +1 self-loop
        dinv[t] = di;
        float4 w;
        w.x = x[t] * di;
        w.y = x[N_NODES + t] * di;
        w.z = x[2 * N_NODES + t] * di;
        w.w = x[3 * N_NODES + t] * di;
        xd4[t] = w;
        y3t4[t] = make_float4(0.f, 0.f, 0.f, 0.f);
    }
}

// bucketed fill: block bid handles edges with (dst&7)==(bid&7) -> single-writer-XCD
__global__ void k_fill(const int* __restrict__ ei, int* __restrict__ cursor,
                       int* __restrict__ csr) {
    int bid = blockIdx.x;
    int r = bid & 7;
    int e = (bid >> 3) * 256 + threadIdx.x;
    if (e >= N_EDGES) return;
    int d = ei[N_EDGES + e];
    if ((d & 7) != r) return;
    int s = ei[e];
    int pos = atomicAdd(&cursor[d], 1);
    csr[pos] = s;
}

// ---------------- compute ----------------

// layer-1 aggregation, batch-shared, masked full-width (no serial remainder)
__global__ __launch_bounds__(256) void k_agg1(
        const float* __restrict__ dinv, const float4* __restrict__ xd4,
        const int* __restrict__ row, const int* __restrict__ cnt,
        const int* __restrict__ csr, float4* __restrict__ px4) {
    int lt = threadIdx.x;
    int node = blockIdx.x * 64 + (lt >> 2);
    if (node >= N_NODES) return;
    int q = lt & 3;

    int deg = cnt[node];
    int r0 = row[node];
    int last = r0 + deg - 1;
    float4 a = make_float4(0.f, 0.f, 0.f, 0.f);
    if (q == 0) a = xd4[node];        // self
    for (int k = r0 + q; k <= last; k += 16) {
        int b1 = min(k + 4, last), b2 = min(k + 8, last), b3 = min(k + 12, last);
        int i0 = csr[k], i1 = csr[b1], i2 = csr[b2], i3 = csr[b3];
        float4 g0 = xd4[i0], g1 = xd4[i1], g2 = xd4[i2], g3 = xd4[i3];
        float m1 = (k + 4 <= last) ? 1.f : 0.f;
        float m2 = (k + 8 <= last) ? 1.f : 0.f;
        float m3 = (k + 12 <= last) ? 1.f : 0.f;
        a.x += (g0.x + m1 * g1.x) + (m2 * g2.x + m3 * g3.x);
        a.y += (g0.y + m1 * g1.y) + (m2 * g2.y + m3 * g3.y);
        a.z += (g0.z + m1 * g1.z) + (m2 * g2.z + m3 * g3.z);
        a.w += (g0.w + m1 * g1.w) + (m2 * g2.w + m3 * g3.w);
    }
    // quad reduce
#pragma unroll
    for (int m = 1; m <= 2; m <<= 1) {
        a.x += __shfl_xor(a.x, m, 64);
        a.y += __shfl_xor(a.y, m, 64);
        a.z += __shfl_xor(a.z, m, 64);
        a.w += __shfl_xor(a.w, m, 64);
    }
    if (q == 0) {
        float di = dinv[node];
        a.x *= di; a.y *= di; a.z *= di; a.w *= di;
        px4[node] = a;
    }
}

// dense per (b,n): h1 = relu(px*W1+b1); y2 = dinv * (h1@W2), split channel halves
__global__ __launch_bounds__(256) void k_mv(
        const float* __restrict__ dinv, const float4* __restrict__ px4,
        const float* __restrict__ W1, const float* __restrict__ b1,
        const float* __restrict__ W2,
        float* __restrict__ y2a, float* __restrict__ y2b) {
    __shared__ float sW1[C1], sb1[C1], sW2[C1 * C2];
    int lt = threadIdx.x;
    for (int i = lt; i < C1; i += 256) { sW1[i] = W1[i]; sb1[i] = b1[i]; }
    for (int i = lt; i < C1 * C2; i += 256) sW2[i] = W2[i];
    __syncthreads();

    int t = blockIdx.x * 256 + lt;
    if (t >= BN) return;
    int n = t % N_NODES;
    int b = t / N_NODES;
    float di = dinv[n];
    float px = ((const float*)px4)[n * 4 + b];

    float acc[C2];
#pragma unroll
    for (int j = 0; j < C2; j++) acc[j] = 0.0f;

    for (int c = 0; c < C1; c++) {
        float h = fmaxf(px * sW1[c] + sb1[c], 0.0f);
        const float4* rw = (const float4*)&sW2[c * C2];
#pragma unroll
        for (int j4 = 0; j4 < C2 / 4; j4++) {
            float4 w = rw[j4];
            acc[4 * j4 + 0] += h * w.x;
            acc[4 * j4 + 1] += h * w.y;
            acc[4 * j4 + 2] += h * w.z;
            acc[4 * j4 + 3] += h * w.w;
        }
    }

    float4* ya = (float4*)&y2a[(size_t)t * 16];
    float4* yb = (float4*)&y2b[(size_t)t * 16];
#pragma unroll
    for (int j4 = 0; j4 < 4; j4++) {
        float4 v;
        v.x = acc[4 * j4 + 0] * di;
        v.y = acc[4 * j4 + 1] * di;
        v.z = acc[4 * j4 + 2] * di;
        v.w = acc[4 * j4 + 3] * di;
        ya[j4] = v;
        float4 w;
        w.x = acc[16 + 4 * j4 + 0] * di;
        w.y = acc[16 + 4 * j4 + 1] * di;
        w.z = acc[16 + 4 * j4 + 2] * di;
        w.w = acc[16 + 4 * j4 + 3] * di;
        yb[j4] = w;
    }
}

// layer-2 aggregation + fused epilogue + layer-3 transform (XCD-affine, L2-resident)
// masked 8-wide gathers: every load issued, no serial remainder
__global__ __launch_bounds__(256) void k_agg2(
        const float* __restrict__ y2a, const float* __restrict__ y2b,
        const int* __restrict__ row, const int* __restrict__ cnt,
        const int* __restrict__ csr,
        const float* __restrict__ dinv, const float* __restrict__ b2,
        const float* __restrict__ W3, float* __restrict__ y3t) {
    int blk = blockIdx.x;
    int xcd = blk & 7;
    int half = xcd & 1;
    int batch = xcd >> 1;
    int sub = blk >> 3;
    int lt = threadIdx.x;
    int node = sub * 64 + (lt >> 2);
    if (node >= N_NODES) return;
    int q = lt & 3;

    const float4* Y = (const float4*)(half ? y2b : y2a);
    int bbase = batch * N_NODES;
    int idx = bbase + node;

    int deg = cnt[node];
    int r0 = row[node];
    int last = r0 + deg - 1;
    float4 a = Y[(size_t)idx * 4 + q];    // self
    for (int k = r0; k <= last; k += 8) {
        int b1 = min(k + 1, last), b2i = min(k + 2, last), b3 = min(k + 3, last);
        int b4 = min(k + 4, last), b5 = min(k + 5, last), b6 = min(k + 6, last), b7 = min(k + 7, last);
        int i0 = csr[k],  i1 = csr[b1], i2 = csr[b2i], i3 = csr[b3];
        int i4 = csr[b4], i5 = csr[b5], i6 = csr[b6],  i7 = csr[b7];
        float4 v0 = Y[(size_t)(bbase + i0) * 4 + q];
        float4 v1 = Y[(size_t)(bbase + i1) * 4 + q];
        float4 v2 = Y[(size_t)(bbase + i2) * 4 + q];
        float4 v3 = Y[(size_t)(bbase + i3) * 4 + q];
        float4 v4 = Y[(size_t)(bbase + i4) * 4 + q];
        float4 v5 = Y[(size_t)(bbase + i5) * 4 + q];
        float4 v6 = Y[(size_t)(bbase + i6) * 4 + q];
        float4 v7 = Y[(size_t)(bbase + i7) * 4 + q];
        float m1 = (k + 1 <= last) ? 1.f : 0.f;
        float m2 = (k + 2 <= last) ? 1.f : 0.f;
        float m3 = (k + 3 <= last) ? 1.f : 0.f;
        float m4 = (k + 4 <= last) ? 1.f : 0.f;
        float m5 = (k + 5 <= last) ? 1.f : 0.f;
        float m6 = (k + 6 <= last) ? 1.f : 0.f;
        float m7 = (k + 7 <= last) ? 1.f : 0.f;
        a.x += ((v0.x + m1 * v1.x) + (m2 * v2.x + m3 * v3.x)) +
               ((m4 * v4.x + m5 * v5.x) + (m6 * v6.x + m7 * v7.x));
        a.y += ((v0.y + m1 * v1.y) + (m2 * v2.y + m3 * v3.y)) +
               ((m4 * v4.y + m5 * v5.y) + (m6 * v6.y + m7 * v7.y));
        a.z += ((v0.z + m1 * v1.z) + (m2 * v2.z + m3 * v3.z)) +
               ((m4 * v4.z + m5 * v5.z) + (m6 * v6.z + m7 * v7.z));
        a.w += ((v0.w + m1 * v1.w) + (m2 * v2.w + m3 * v3.w)) +
               ((m4 * v4.w + m5 * v5.w) + (m6 * v6.w + m7 * v7.w));
    }

    float di = dinv[node];
    int c0 = half * 16 + q * 4;
    float p = fmaxf(di * a.x + b2[c0 + 0], 0.0f) * W3[c0 + 0]
            + fmaxf(di * a.y + b2[c0 + 1], 0.0f) * W3[c0 + 1]
            + fmaxf(di * a.z + b2[c0 + 2], 0.0f) * W3[c0 + 2]
            + fmaxf(di * a.w + b2[c0 + 3], 0.0f) * W3[c0 + 3];
    p += __shfl_xor(p, 1, 64);
    p += __shfl_xor(p, 2, 64);
    if (q == 0) atomicAdd(&y3t[node * 4 + batch], di * p);
}

// layer-3 aggregation + sigmoid, batch-shared float4 gathers, masked full-width
__global__ __launch_bounds__(256) void k_agg3(
        const float* __restrict__ dinv, const float4* __restrict__ y3t,
        const int* __restrict__ row, const int* __restrict__ cnt,
        const int* __restrict__ csr,
        const float* __restrict__ b3, float* __restrict__ out) {
    int lt = threadIdx.x;
    int node = blockIdx.x * 64 + (lt >> 2);
    if (node >= N_NODES) return;
    int q = lt & 3;

    int deg = cnt[node];
    int r0 = row[node];
    int last = r0 + deg - 1;
    float4 a = make_float4(0.f, 0.f, 0.f, 0.f);
    if (q == 0) a = y3t[node];        // self
    for (int k = r0 + q; k <= last; k += 16) {
        int b1 = min(k + 4, last), b2 = min(k + 8, last), b3i = min(k + 12, last);
        int i0 = csr[k], i1 = csr[b1], i2 = csr[b2], i3 = csr[b3i];
        float4 g0 = y3t[i0], g1 = y3t[i1], g2 = y3t[i2], g3 = y3t[i3];
        float m1 = (k + 4 <= last) ? 1.f : 0.f;
        float m2 = (k + 8 <= last) ? 1.f : 0.f;
        float m3 = (k + 12 <= last) ? 1.f : 0.f;
        a.x += (g0.x + m1 * g1.x) + (m2 * g2.x + m3 * g3.x);
        a.y += (g0.y + m1 * g1.y) + (m2 * g2.y + m3 * g3.y);
        a.z += (g0.z + m1 * g1.z) + (m2 * g2.z + m3 * g3.z);
        a.w += (g0.w + m1 * g1.w) + (m2 * g2.w + m3 * g3.w);
    }
#pragma unroll
    for (int m = 1; m <= 2; m <<= 1) {
        a.x += __shfl_xor(a.x, m, 64);
        a.y += __shfl_xor(a.y, m, 64);
        a.z += __shfl_xor(a.z, m, 64);
        a.w += __shfl_xor(a.w, m, 64);
    }
    if (q == 0) {
        float di = dinv[node];
        float bb = b3[0];
        out[0 * N_NODES + node] = 1.0f / (1.0f + expf(-(di * a.x + bb)));
        out[1 * N_NODES + node] = 1.0f / (1.0f + expf(-(di * a.y + bb)));
        out[2 * N_NODES + node] = 1.0f / (1.0f + expf(-(di * a.z + bb)));
        out[3 * N_NODES + node] = 1.0f / (1.0f + expf(-(di * a.w + bb)));
    }
}

// ---------------- launch ----------------

extern "C" void kernel_launch(void* const* d_in, const int* in_sizes, int n_in,
                              void* d_out, int out_size, void* d_ws, size_t ws_size,
                              hipStream_t stream) {
    const float* x   = (const float*)d_in[0];
    const int*   ei  = (const int*)d_in[1];
    const float* W1  = (const float*)d_in[2];
    const float* b1  = (const float*)d_in[3];
    const float* W2  = (const float*)d_in[4];
    const float* b2  = (const float*)d_in[5];
    const float* W3  = (const float*)d_in[6];
    const float* b3  = (const float*)d_in[7];
    float* out = (float*)d_out;

    char* ws = (char*)d_ws;
    size_t off = 0;
    auto carve = [&](size_t bytes) {
        void* p = ws + off;
        off = (off + bytes + 255) & ~(size_t)255;
        return p;
    };
    int*    cnt    = (int*)   carve(N_NODES * 4);
    int*    row    = (int*)   carve(N_NODES * 4);
    int*    cursor = (int*)   carve(N_NODES * 4);
    float*  dinv   = (float*) carve(N_NODES * 4);
    int*    csr    = (int*)   carve(N_EDGES * 4);
    float4* xd4    = (float4*)carve((size_t)N_NODES * 16);
    float4* px4    = (float4*)carve((size_t)N_NODES * 16);
    float*  y2a    = (float*) carve((size_t)BN * 16 * 4);
    float*  y2b    = (float*) carve((size_t)BN * 16 * 4);
    float*  y3t    = (float*) carve((size_t)N_NODES * 16);
    int*    cur8   = (int*)   carve(8 * 4);

    dim3 blk(256);

    k_zero     <<<NBLK_N, blk, 0, stream>>>(cnt);
    k_hist     <<<(N_EDGES + 255) / 256, blk, 0, stream>>>(ei, cnt);
    k_bcur     <<<1, 1024, 0, stream>>>(cnt, cur8);
    k_alloc_xd <<<NBLK_N, blk, 0, stream>>>(cnt, x, row, cursor, dinv, xd4, (float4*)y3t, cur8);
    k_fill     <<<8 * ((N_EDGES + 255) / 256), blk, 0, stream>>>(ei, cursor, csr);
    k_agg1     <<<NBLK_Q, blk, 0, stream>>>(dinv, xd4, row, cnt, csr, px4);
    k_mv       <<<(BN + 255) / 256, blk, 0, stream>>>(dinv, px4, W1, b1, W2, y2a, y2b);
    k_agg2     <<<8 * NBLK_Q, blk, 0, stream>>>(y2a, y2b, row, cnt, csr, dinv, b2, W3, y3t);
    k_agg3     <<<NBLK_Q, blk, 0, stream>>>(dinv, (const float4*)y3t, row, cnt, csr, b3, out);
}

// Round 9
// 181.382 us; speedup vs baseline: 1.6315x; 1.3962x over previous
//
#include <hip/hip_runtime.h>
#include <hip/hip_fp16.h>
#include <math.h>

#define N_NODES 50000
#define N_EDGES 800000
#define BATCH   4
#define C1      64
#define C2      32
#define BN      (BATCH * N_NODES)
#define ELL_CAP 64
#define NHALF   (N_NODES / 2)
#define NBLK_N  ((N_NODES + 255) / 256)
#define NBLK_Q  ((N_NODES + 63) / 64)    // 4 lanes/node
#define NBLK_H  ((NHALF + 63) / 64)      // 4 lanes/node, half the nodes

// ---------------- build ----------------

// zero the (padded-to-64B) per-node edge counters
__global__ void k_zero(int* __restrict__ cnt16) {
    int n = blockIdx.x * 256 + threadIdx.x;
    if (n < N_NODES) cnt16[n * 16] = 0;
}

// bucketed single-pass ELL fill: block bid handles edges with (dst&7)==(bid&7).
// cnt16 padded to one line/node and ell rows are 256B -> single-writer-XCD lines.
__global__ void k_fill(const int* __restrict__ ei, int* __restrict__ cnt16,
                       int* __restrict__ ell) {
    int bid = blockIdx.x;
    int r = bid & 7;
    int e = (bid >> 3) * 256 + threadIdx.x;
    if (e >= N_EDGES) return;
    int d = ei[N_EDGES + e];
    if ((d & 7) != r) return;
    int s = ei[e];
    int pos = atomicAdd(&cnt16[d * 16], 1);
    if (pos < ELL_CAP) ell[d * ELL_CAP + pos] = s;
}

// per node: compact degree, dinv, xd4 = x * dinv (batch-transposed)
__global__ void k_prep(const int* __restrict__ cnt16, const float* __restrict__ x,
                       int* __restrict__ degc, float* __restrict__ dinv,
                       float4* __restrict__ xd4) {
    int n = blockIdx.x * 256 + threadIdx.x;
    if (n >= N_NODES) return;
    int deg = cnt16[n * 16];
    degc[n] = deg;
    float di = rsqrtf((float)(deg + 1));   // +1 self-loop
    dinv[n] = di;
    float4 w;
    w.x = x[n] * di;
    w.y = x[N_NODES + n] * di;
    w.z = x[2 * N_NODES + n] * di;
    w.w = x[3 * N_NODES + n] * di;
    xd4[n] = w;
}

// ---------------- compute ----------------

// layer-1 aggregation, batch-shared float4 gathers, masked full-width, ELL rows
__global__ __launch_bounds__(256) void k_agg1(
        const float* __restrict__ dinv, const float4* __restrict__ xd4,
        const int* __restrict__ degc, const int* __restrict__ ell,
        float4* __restrict__ px4) {
    int lt = threadIdx.x;
    int node = blockIdx.x * 64 + (lt >> 2);
    if (node >= N_NODES) return;
    int q = lt & 3;

    int deg = degc[node];
    const int* rowp = ell + node * ELL_CAP;
    int last = deg - 1;
    float4 a = make_float4(0.f, 0.f, 0.f, 0.f);
    if (q == 0) a = xd4[node];        // self
    for (int k = q; k <= last; k += 16) {
        int b1 = min(k + 4, last), b2 = min(k + 8, last), b3 = min(k + 12, last);
        int i0 = rowp[k], i1 = rowp[b1], i2 = rowp[b2], i3 = rowp[b3];
        float4 g0 = xd4[i0], g1 = xd4[i1], g2 = xd4[i2], g3 = xd4[i3];
        float m1 = (k + 4 <= last) ? 1.f : 0.f;
        float m2 = (k + 8 <= last) ? 1.f : 0.f;
        float m3 = (k + 12 <= last) ? 1.f : 0.f;
        a.x += (g0.x + m1 * g1.x) + (m2 * g2.x + m3 * g3.x);
        a.y += (g0.y + m1 * g1.y) + (m2 * g2.y + m3 * g3.y);
        a.z += (g0.z + m1 * g1.z) + (m2 * g2.z + m3 * g3.z);
        a.w += (g0.w + m1 * g1.w) + (m2 * g2.w + m3 * g3.w);
    }
#pragma unroll
    for (int m = 1; m <= 2; m <<= 1) {
        a.x += __shfl_xor(a.x, m, 64);
        a.y += __shfl_xor(a.y, m, 64);
        a.z += __shfl_xor(a.z, m, 64);
        a.w += __shfl_xor(a.w, m, 64);
    }
    if (q == 0) {
        float di = dinv[node];
        a.x *= di; a.y *= di; a.z *= di; a.w *= di;
        px4[node] = a;
    }
}

// dense per (b,n): h1 = relu(px*W1+b1); y2 = dinv*(h1@W2) stored as fp16
// layout y2h[batch][node][32] -> 64B row, one L2 line per (b,node)
__global__ __launch_bounds__(256) void k_mv(
        const float* __restrict__ dinv, const float4* __restrict__ px4,
        const float* __restrict__ W1, const float* __restrict__ b1,
        const float* __restrict__ W2, __half* __restrict__ y2h) {
    __shared__ float sW1[C1], sb1[C1], sW2[C1 * C2];
    int lt = threadIdx.x;
    for (int i = lt; i < C1; i += 256) { sW1[i] = W1[i]; sb1[i] = b1[i]; }
    for (int i = lt; i < C1 * C2; i += 256) sW2[i] = W2[i];
    __syncthreads();

    int t = blockIdx.x * 256 + lt;
    if (t >= BN) return;
    int b = t / N_NODES;
    int n = t - b * N_NODES;
    float di = dinv[n];
    float px = ((const float*)px4)[n * 4 + b];

    float acc[C2];
#pragma unroll
    for (int j = 0; j < C2; j++) acc[j] = 0.0f;

    for (int c = 0; c < C1; c++) {
        float h = fmaxf(px * sW1[c] + sb1[c], 0.0f);
        const float4* rw = (const float4*)&sW2[c * C2];
#pragma unroll
        for (int j4 = 0; j4 < C2 / 4; j4++) {
            float4 w = rw[j4];
            acc[4 * j4 + 0] += h * w.x;
            acc[4 * j4 + 1] += h * w.y;
            acc[4 * j4 + 2] += h * w.z;
            acc[4 * j4 + 3] += h * w.w;
        }
    }

    __half2 hbuf[16];
#pragma unroll
    for (int j = 0; j < 16; j++)
        hbuf[j] = __floats2half2_rn(acc[2 * j] * di, acc[2 * j + 1] * di);
    float4* dst = (float4*)(y2h + (size_t)t * 32);
    const float4* srcb = (const float4*)hbuf;
#pragma unroll
    for (int j4 = 0; j4 < 4; j4++) dst[j4] = srcb[j4];
}

// add 8 fp16 channels (one 16B chunk) into fp32 accumulator with mask
__device__ __forceinline__ void acc8(float* a, float4 raw, float m) {
    const __half2* hp = (const __half2*)&raw;
#pragma unroll
    for (int j = 0; j < 4; j++) {
        float2 f = __half22float2(hp[j]);
        a[2 * j + 0] += m * f.x;
        a[2 * j + 1] += m * f.y;
    }
}

// layer-2 aggregation (fp16 rows, 1 line/edge/batch) + epilogue + layer-3 transform.
// XCD-affine: xcd=blk&7 -> batch=xcd>>1, nodehalf=xcd&1; per-XCD table 3.2MB (L2-fit).
// Quad = one (node,batch); lane q holds channels q*8..q*8+7. Plain store (unique writer).
__global__ __launch_bounds__(256) void k_agg2(
        const __half* __restrict__ y2h, const int* __restrict__ degc,
        const int* __restrict__ ell, const float* __restrict__ dinv,
        const float* __restrict__ b2, const float* __restrict__ W3,
        float* __restrict__ y3t) {
    int blk = blockIdx.x;
    int xcd = blk & 7;
    int batch = xcd >> 1;
    int nh = xcd & 1;
    int sub = blk >> 3;
    int lt = threadIdx.x;
    int unit = sub * 64 + (lt >> 2);
    if (unit >= NHALF) return;
    int node = nh * NHALF + unit;
    int q = lt & 3;

    const float4* Yb = (const float4*)(y2h + (size_t)batch * N_NODES * 32);

    float a[8];
    {   // self
        float4 raw = Yb[(size_t)node * 4 + q];
        const __half2* hp = (const __half2*)&raw;
#pragma unroll
        for (int j = 0; j < 4; j++) {
            float2 f = __half22float2(hp[j]);
            a[2 * j + 0] = f.x;
            a[2 * j + 1] = f.y;
        }
    }

    int deg = degc[node];
    const int* rowp = ell + node * ELL_CAP;
    int last = deg - 1;
    for (int k = 0; k <= last; k += 4) {
        int c1 = min(k + 1, last), c2 = min(k + 2, last), c3 = min(k + 3, last);
        int i0 = rowp[k], i1 = rowp[c1], i2 = rowp[c2], i3 = rowp[c3];
        float4 r0 = Yb[(size_t)i0 * 4 + q];
        float4 r1 = Yb[(size_t)i1 * 4 + q];
        float4 r2 = Yb[(size_t)i2 * 4 + q];
        float4 r3 = Yb[(size_t)i3 * 4 + q];
        float m1 = (k + 1 <= last) ? 1.f : 0.f;
        float m2 = (k + 2 <= last) ? 1.f : 0.f;
        float m3 = (k + 3 <= last) ? 1.f : 0.f;
        acc8(a, r0, 1.f);
        acc8(a, r1, m1);
        acc8(a, r2, m2);
        acc8(a, r3, m3);
    }

    float di = dinv[node];
    int c0 = q * 8;
    float p = 0.f;
#pragma unroll
    for (int j = 0; j < 8; j++)
        p += fmaxf(di * a[j] + b2[c0 + j], 0.0f) * W3[c0 + j];
    p += __shfl_xor(p, 1, 64);
    p += __shfl_xor(p, 2, 64);
    if (q == 0) y3t[node * 4 + batch] = di * p;   // unique writer, no atomic
}

// layer-3 aggregation + sigmoid, batch-shared float4 gathers, ELL rows
__global__ __launch_bounds__(256) void k_agg3(
        const float* __restrict__ dinv, const float4* __restrict__ y3t,
        const int* __restrict__ degc, const int* __restrict__ ell,
        const float* __restrict__ b3, float* __restrict__ out) {
    int lt = threadIdx.x;
    int node = blockIdx.x * 64 + (lt >> 2);
    if (node >= N_NODES) return;
    int q = lt & 3;

    int deg = degc[node];
    const int* rowp = ell + node * ELL_CAP;
    int last = deg - 1;
    float4 a = make_float4(0.f, 0.f, 0.f, 0.f);
    if (q == 0) a = y3t[node];        // self
    for (int k = q; k <= last; k += 16) {
        int b1 = min(k + 4, last), b2 = min(k + 8, last), b3i = min(k + 12, last);
        int i0 = rowp[k], i1 = rowp[b1], i2 = rowp[b2], i3 = rowp[b3i];
        float4 g0 = y3t[i0], g1 = y3t[i1], g2 = y3t[i2], g3 = y3t[i3];
        float m1 = (k + 4 <= last) ? 1.f : 0.f;
        float m2 = (k + 8 <= last) ? 1.f : 0.f;
        float m3 = (k + 12 <= last) ? 1.f : 0.f;
        a.x += (g0.x + m1 * g1.x) + (m2 * g2.x + m3 * g3.x);
        a.y += (g0.y + m1 * g1.y) + (m2 * g2.y + m3 * g3.y);
        a.z += (g0.z + m1 * g1.z) + (m2 * g2.z + m3 * g3.z);
        a.w += (g0.w + m1 * g1.w) + (m2 * g2.w + m3 * g3.w);
    }
#pragma unroll
    for (int m = 1; m <= 2; m <<= 1) {
        a.x += __shfl_xor(a.x, m, 64);
        a.y += __shfl_xor(a.y, m, 64);
        a.z += __shfl_xor(a.z, m, 64);
        a.w += __shfl_xor(a.w, m, 64);
    }
    if (q == 0) {
        float di = dinv[node];
        float bb = b3[0];
        out[0 * N_NODES + node] = 1.0f / (1.0f + expf(-(di * a.x + bb)));
        out[1 * N_NODES + node] = 1.0f / (1.0f + expf(-(di * a.y + bb)));
        out[2 * N_NODES + node] = 1.0f / (1.0f + expf(-(di * a.z + bb)));
        out[3 * N_NODES + node] = 1.0f / (1.0f + expf(-(di * a.w + bb)));
    }
}

// ---------------- launch ----------------

extern "C" void kernel_launch(void* const* d_in, const int* in_sizes, int n_in,
                              void* d_out, int out_size, void* d_ws, size_t ws_size,
                              hipStream_t stream) {
    const float* x   = (const float*)d_in[0];
    const int*   ei  = (const int*)d_in[1];
    const float* W1  = (const float*)d_in[2];
    const float* b1  = (const float*)d_in[3];
    const float* W2  = (const float*)d_in[4];
    const float* b2  = (const float*)d_in[5];
    const float* W3  = (const float*)d_in[6];
    const float* b3  = (const float*)d_in[7];
    float* out = (float*)d_out;

    char* ws = (char*)d_ws;
    size_t off = 0;
    auto carve = [&](size_t bytes) {
        void* p = ws + off;
        off = (off + bytes + 255) & ~(size_t)255;
        return p;
    };
    int*    cnt16 = (int*)   carve((size_t)N_NODES * 16 * 4);
    int*    ell   = (int*)   carve((size_t)N_NODES * ELL_CAP * 4);
    int*    degc  = (int*)   carve(N_NODES * 4);
    float*  dinv  = (float*) carve(N_NODES * 4);
    float4* xd4   = (float4*)carve((size_t)N_NODES * 16);
    float4* px4   = (float4*)carve((size_t)N_NODES * 16);
    __half* y2h   = (__half*)carve((size_t)BN * 32 * 2);
    float*  y3t   = (float*) carve((size_t)N_NODES * 16);

    dim3 blk(256);

    k_zero <<<NBLK_N, blk, 0, stream>>>(cnt16);
    k_fill <<<8 * ((N_EDGES + 255) / 256), blk, 0, stream>>>(ei, cnt16, ell);
    k_prep <<<NBLK_N, blk, 0, stream>>>(cnt16, x, degc, dinv, xd4);
    k_agg1 <<<NBLK_Q, blk, 0, stream>>>(dinv, xd4, degc, ell, px4);
    k_mv   <<<(BN + 255) / 256, blk, 0, stream>>>(dinv, px4, W1, b1, W2, y2h);
    k_agg2 <<<8 * NBLK_H, blk, 0, stream>>>(y2h, degc, ell, dinv, b2, W3, y3t);
    k_agg3 <<<NBLK_Q, blk, 0, stream>>>(dinv, (const float4*)y3t, degc, ell, b3, out);
}

// Round 10
// 175.035 us; speedup vs baseline: 1.6906x; 1.0363x over previous
//
#include <hip/hip_runtime.h>
#include <hip/hip_fp16.h>
#include <math.h>

#define N_NODES 50000
#define N_EDGES 800000
#define BATCH   4
#define C1      64
#define C2      32
#define BN      (BATCH * N_NODES)
#define ELL_CAP 64
#define NHALF   (N_NODES / 2)
#define NBLK_N  ((N_NODES + 255) / 256)
#define NBLK_Q  ((N_NODES + 63) / 64)    // 4 lanes/node
#define NBLK_H8 ((NHALF + 31) / 32)      // 8 lanes/unit, half the nodes
#define NBLK_N8 ((N_NODES + 31) / 32)    // 8 lanes/node

typedef unsigned short u16;

// ---------------- build ----------------

// zero the (padded-to-64B) per-node edge counters
__global__ void k_zero(int* __restrict__ cnt16) {
    int n = blockIdx.x * 256 + threadIdx.x;
    if (n < N_NODES) cnt16[n * 16] = 0;
}

// bucketed single-pass ELL fill: block bid handles edges with (dst&7)==(bid&7).
// cnt16 padded to one line/node; ell rows 128B (u16) -> single-writer-XCD lines.
__global__ void k_fill(const int* __restrict__ ei, int* __restrict__ cnt16,
                       u16* __restrict__ ell) {
    int bid = blockIdx.x;
    int r = bid & 7;
    int e = (bid >> 3) * 256 + threadIdx.x;
    if (e >= N_EDGES) return;
    int d = ei[N_EDGES + e];
    if ((d & 7) != r) return;
    int s = ei[e];
    int pos = atomicAdd(&cnt16[d * 16], 1);
    if (pos < ELL_CAP) ell[d * ELL_CAP + pos] = (u16)s;
}

// per node: compact degree, dinv, xd4 = x * dinv (batch-transposed)
__global__ void k_prep(const int* __restrict__ cnt16, const float* __restrict__ x,
                       int* __restrict__ degc, float* __restrict__ dinv,
                       float4* __restrict__ xd4) {
    int n = blockIdx.x * 256 + threadIdx.x;
    if (n >= N_NODES) return;
    int deg = cnt16[n * 16];
    degc[n] = deg;
    float di = rsqrtf((float)(deg + 1));   // +1 self-loop
    dinv[n] = di;
    float4 w;
    w.x = x[n] * di;
    w.y = x[N_NODES + n] * di;
    w.z = x[2 * N_NODES + n] * di;
    w.w = x[3 * N_NODES + n] * di;
    xd4[n] = w;
}

// ---------------- compute ----------------

// fused: layer-1 aggregation (4 lanes/node, batch-shared float4 gathers) +
// dense matvec per lane (lane q = batch q): h1=relu(px*W1+b1); y2=dinv*(h1@W2) fp16
__global__ __launch_bounds__(256) void k_agg1mv(
        const float* __restrict__ dinv, const float4* __restrict__ xd4,
        const int* __restrict__ degc, const u16* __restrict__ ell,
        const float* __restrict__ W1, const float* __restrict__ b1,
        const float* __restrict__ W2, __half* __restrict__ y2h) {
    __shared__ float sW1[C1], sb1[C1], sW2[C1 * C2];
    int lt = threadIdx.x;
    for (int i = lt; i < C1; i += 256) { sW1[i] = W1[i]; sb1[i] = b1[i]; }
    for (int i = lt; i < C1 * C2; i += 256) sW2[i] = W2[i];
    __syncthreads();

    int node = blockIdx.x * 64 + (lt >> 2);
    if (node >= N_NODES) return;
    int q = lt & 3;

    int deg = degc[node];
    const u16* rowp = ell + node * ELL_CAP;
    int last = deg - 1;
    float4 a = make_float4(0.f, 0.f, 0.f, 0.f);
    if (q == 0) a = xd4[node];        // self
    for (int k = q; k <= last; k += 16) {
        int e1 = min(k + 4, last), e2 = min(k + 8, last), e3 = min(k + 12, last);
        int i0 = rowp[k], i1 = rowp[e1], i2 = rowp[e2], i3 = rowp[e3];
        float4 g0 = xd4[i0], g1 = xd4[i1], g2 = xd4[i2], g3 = xd4[i3];
        float m1 = (k + 4 <= last) ? 1.f : 0.f;
        float m2 = (k + 8 <= last) ? 1.f : 0.f;
        float m3 = (k + 12 <= last) ? 1.f : 0.f;
        a.x += (g0.x + m1 * g1.x) + (m2 * g2.x + m3 * g3.x);
        a.y += (g0.y + m1 * g1.y) + (m2 * g2.y + m3 * g3.y);
        a.z += (g0.z + m1 * g1.z) + (m2 * g2.z + m3 * g3.z);
        a.w += (g0.w + m1 * g1.w) + (m2 * g2.w + m3 * g3.w);
    }
#pragma unroll
    for (int m = 1; m <= 2; m <<= 1) {
        a.x += __shfl_xor(a.x, m, 64);
        a.y += __shfl_xor(a.y, m, 64);
        a.z += __shfl_xor(a.z, m, 64);
        a.w += __shfl_xor(a.w, m, 64);
    }

    float di = dinv[node];
    float px = (q == 0) ? a.x : (q == 1) ? a.y : (q == 2) ? a.z : a.w;
    px *= di;                          // lane q <- propagated input for batch q

    float acc[C2];
#pragma unroll
    for (int j = 0; j < C2; j++) acc[j] = 0.0f;
    for (int c = 0; c < C1; c++) {
        float h = fmaxf(px * sW1[c] + sb1[c], 0.0f);
        const float4* rw = (const float4*)&sW2[c * C2];
#pragma unroll
        for (int j4 = 0; j4 < C2 / 4; j4++) {
            float4 w = rw[j4];
            acc[4 * j4 + 0] += h * w.x;
            acc[4 * j4 + 1] += h * w.y;
            acc[4 * j4 + 2] += h * w.z;
            acc[4 * j4 + 3] += h * w.w;
        }
    }

    __half2 hbuf[16];
#pragma unroll
    for (int j = 0; j < 16; j++)
        hbuf[j] = __floats2half2_rn(acc[2 * j] * di, acc[2 * j + 1] * di);
    float4* dst = (float4*)(y2h + ((size_t)q * N_NODES + node) * 32);
    const float4* srcb = (const float4*)hbuf;
#pragma unroll
    for (int j4 = 0; j4 < 4; j4++) dst[j4] = srcb[j4];
}

// add 8 fp16 channels (one 16B chunk) into fp32 accumulator with mask
__device__ __forceinline__ void acc8(float* a, float4 raw, float m) {
    const __half2* hp = (const __half2*)&raw;
#pragma unroll
    for (int j = 0; j < 4; j++) {
        float2 f = __half22float2(hp[j]);
        a[2 * j + 0] += m * f.x;
        a[2 * j + 1] += m * f.y;
    }
}

// layer-2 aggregation (fp16 64B rows, 1 line/edge/batch) + epilogue + layer-3 dot.
// XCD-affine: xcd=blk&7 -> batch=xcd>>1, nodehalf=xcd&1 (slice ~4.8MB ~ L2-fit).
// 8 lanes/unit: o=edge parity, q=channel chunk. Unique writer -> plain store.
__global__ __launch_bounds__(256) void k_agg2(
        const __half* __restrict__ y2h, const int* __restrict__ degc,
        const u16* __restrict__ ell, const float* __restrict__ dinv,
        const float* __restrict__ b2, const float* __restrict__ W3,
        float* __restrict__ y3t) {
    int blk = blockIdx.x;
    int xcd = blk & 7;
    int batch = xcd >> 1;
    int nh = xcd & 1;
    int sub = blk >> 3;
    int lt = threadIdx.x;
    int unit = sub * 32 + (lt >> 3);
    if (unit >= NHALF) return;
    int node = nh * NHALF + unit;
    int o = (lt >> 2) & 1;
    int q = lt & 3;

    const float4* Yb = (const float4*)(y2h + (size_t)batch * N_NODES * 32);

    float a[8];
#pragma unroll
    for (int j = 0; j < 8; j++) a[j] = 0.f;
    if (o == 0) {   // self
        float4 raw = Yb[(size_t)node * 4 + q];
        acc8(a, raw, 1.f);
    }

    int deg = degc[node];
    const u16* rowp = ell + node * ELL_CAP;
    int last = deg - 1;
    for (int kb = 0; kb <= last; kb += 8) {
        int k0 = kb + o, k1 = kb + 2 + o, k2 = kb + 4 + o, k3 = kb + 6 + o;
        int e0 = min(k0, last), e1 = min(k1, last), e2 = min(k2, last), e3 = min(k3, last);
        int i0 = rowp[e0], i1 = rowp[e1], i2 = rowp[e2], i3 = rowp[e3];
        float4 r0 = Yb[(size_t)i0 * 4 + q];
        float4 r1 = Yb[(size_t)i1 * 4 + q];
        float4 r2 = Yb[(size_t)i2 * 4 + q];
        float4 r3 = Yb[(size_t)i3 * 4 + q];
        float m0 = (k0 <= last) ? 1.f : 0.f;
        float m1 = (k1 <= last) ? 1.f : 0.f;
        float m2 = (k2 <= last) ? 1.f : 0.f;
        float m3 = (k3 <= last) ? 1.f : 0.f;
        acc8(a, r0, m0);
        acc8(a, r1, m1);
        acc8(a, r2, m2);
        acc8(a, r3, m3);
    }

    // reduce over edge-parity (xor 4)
#pragma unroll
    for (int j = 0; j < 8; j++) a[j] += __shfl_xor(a[j], 4, 64);

    float di = dinv[node];
    int c0 = q * 8;
    float p = 0.f;
#pragma unroll
    for (int j = 0; j < 8; j++)
        p += fmaxf(di * a[j] + b2[c0 + j], 0.0f) * W3[c0 + j];
    p += __shfl_xor(p, 1, 64);
    p += __shfl_xor(p, 2, 64);
    if ((lt & 7) == 0) y3t[node * 4 + batch] = di * p;   // unique writer
}

// layer-3 aggregation + sigmoid; 8 lanes/node, unroll-2 (16 edges in flight)
__global__ __launch_bounds__(256) void k_agg3(
        const float* __restrict__ dinv, const float4* __restrict__ y3t,
        const int* __restrict__ degc, const u16* __restrict__ ell,
        const float* __restrict__ b3, float* __restrict__ out) {
    int lt = threadIdx.x;
    int node = blockIdx.x * 32 + (lt >> 3);
    if (node >= N_NODES) return;
    int l8 = lt & 7;

    int deg = degc[node];
    const u16* rowp = ell + node * ELL_CAP;
    int last = deg - 1;
    float4 a = make_float4(0.f, 0.f, 0.f, 0.f);
    if (l8 == 0) a = y3t[node];       // self
    for (int k = l8; k <= last; k += 16) {
        int e1 = min(k + 8, last);
        int i0 = rowp[k], i1 = rowp[e1];
        float4 g0 = y3t[i0], g1 = y3t[i1];
        float m1 = (k + 8 <= last) ? 1.f : 0.f;
        a.x += g0.x + m1 * g1.x;
        a.y += g0.y + m1 * g1.y;
        a.z += g0.z + m1 * g1.z;
        a.w += g0.w + m1 * g1.w;
    }
#pragma unroll
    for (int m = 1; m <= 4; m <<= 1) {
        a.x += __shfl_xor(a.x, m, 64);
        a.y += __shfl_xor(a.y, m, 64);
        a.z += __shfl_xor(a.z, m, 64);
        a.w += __shfl_xor(a.w, m, 64);
    }
    if (l8 == 0) {
        float di = dinv[node];
        float bb = b3[0];
        out[0 * N_NODES + node] = 1.0f / (1.0f + expf(-(di * a.x + bb)));
        out[1 * N_NODES + node] = 1.0f / (1.0f + expf(-(di * a.y + bb)));
        out[2 * N_NODES + node] = 1.0f / (1.0f + expf(-(di * a.z + bb)));
        out[3 * N_NODES + node] = 1.0f / (1.0f + expf(-(di * a.w + bb)));
    }
}

// ---------------- launch ----------------

extern "C" void kernel_launch(void* const* d_in, const int* in_sizes, int n_in,
                              void* d_out, int out_size, void* d_ws, size_t ws_size,
                              hipStream_t stream) {
    const float* x   = (const float*)d_in[0];
    const int*   ei  = (const int*)d_in[1];
    const float* W1  = (const float*)d_in[2];
    const float* b1  = (const float*)d_in[3];
    const float* W2  = (const float*)d_in[4];
    const float* b2  = (const float*)d_in[5];
    const float* W3  = (const float*)d_in[6];
    const float* b3  = (const float*)d_in[7];
    float* out = (float*)d_out;

    char* ws = (char*)d_ws;
    size_t off = 0;
    auto carve = [&](size_t bytes) {
        void* p = ws + off;
        off = (off + bytes + 255) & ~(size_t)255;
        return p;
    };
    int*    cnt16 = (int*)   carve((size_t)N_NODES * 16 * 4);
    u16*    ell   = (u16*)   carve((size_t)N_NODES * ELL_CAP * 2);
    int*    degc  = (int*)   carve(N_NODES * 4);
    float*  dinv  = (float*) carve(N_NODES * 4);
    float4* xd4   = (float4*)carve((size_t)N_NODES * 16);
    __half* y2h   = (__half*)carve((size_t)BN * 32 * 2);
    float*  y3t   = (float*) carve((size_t)N_NODES * 16);

    dim3 blk(256);

    k_zero   <<<NBLK_N, blk, 0, stream>>>(cnt16);
    k_fill   <<<8 * ((N_EDGES + 255) / 256), blk, 0, stream>>>(ei, cnt16, ell);
    k_prep   <<<NBLK_N, blk, 0, stream>>>(cnt16, x, degc, dinv, xd4);
    k_agg1mv <<<NBLK_Q, blk, 0, stream>>>(dinv, xd4, degc, ell, W1, b1, W2, y2h);
    k_agg2   <<<8 * NBLK_H8, blk, 0, stream>>>(y2h, degc, ell, dinv, b2, W3, y3t);
    k_agg3   <<<NBLK_N8, blk, 0, stream>>>(dinv, (const float4*)y3t, degc, ell, b3, out);
}